// Round 1
// baseline (389.251 us; speedup 1.0000x reference)
//
#include <hip/hip_runtime.h>

typedef unsigned short u16;
typedef __attribute__((ext_vector_type(8))) short bf16x8;
typedef __attribute__((ext_vector_type(4))) float f32x4;

#define S_LEN 2048
#define NHEAD 16
#define DHEAD 64
#define DMODEL 1024
#define BATCH 4

__device__ __forceinline__ u16 f2bf(float f) {
  unsigned u = __builtin_bit_cast(unsigned, f);
  unsigned r = (u + 0x7fffu + ((u >> 16) & 1u)) >> 16;
  return (u16)r;
}

__device__ __forceinline__ void gld_lds16(const void* g, void* l) {
  __builtin_amdgcn_global_load_lds((const __attribute__((address_space(1))) unsigned*)g,
                                   (__attribute__((address_space(3))) unsigned*)l,
                                   16, 0, 0);
}

__global__ void cast_bf16_kernel(const float* __restrict__ in, u16* __restrict__ out, int n4) {
  int i = blockIdx.x * 256 + threadIdx.x;
  if (i >= n4) return;
  float4 v = reinterpret_cast<const float4*>(in)[i];
  ushort4 o;
  o.x = f2bf(v.x); o.y = f2bf(v.y); o.z = f2bf(v.z); o.w = f2bf(v.w);
  reinterpret_cast<ushort4*>(out)[i] = o;
}

// C = A (M x K) * B^T where B is (N x K) row-major. K = DMODEL = 1024. 128x128 tile, BK=32.
// mode 0: write Q bf16 [B][H][S][DH], scale 0.125 (1/sqrt(DH))
// mode 1: write K bf16 [B][H][S][DH]
// mode 2: write V bf16 transposed [B*H][DH][S]
// mode 3: write fp32 [M][N] row-major (final output projection)
__global__ __launch_bounds__(256) void gemm_bt(const u16* __restrict__ A, const u16* __restrict__ Bw,
                                               void* __restrict__ outp, int mode) {
  __shared__ u16 lA[128 * 32];
  __shared__ u16 lB[128 * 32];
  const int tid = threadIdx.x;
  const int w = tid >> 6, lane = tid & 63;
  const int wm = w >> 1, wn = w & 1;
  const int c = lane & 15, qr = lane >> 4;
  const int brow = blockIdx.y * 128;
  const int bcol = blockIdx.x * 128;
  f32x4 acc[4][4];
#pragma unroll
  for (int m = 0; m < 4; ++m)
#pragma unroll
    for (int n = 0; n < 4; ++n) acc[m][n] = (f32x4){0.f, 0.f, 0.f, 0.f};

  for (int kt = 0; kt < 32; ++kt) {
    const int k0 = kt * 32;
#pragma unroll
    for (int i = 0; i < 2; ++i) {
      int slot = i * 256 + w * 64 + lane;
      int r = slot >> 2, sg = slot & 3;
      gld_lds16(A + (size_t)(brow + r) * DMODEL + k0 + sg * 8, lA + (i * 256 + w * 64) * 8);
      gld_lds16(Bw + (size_t)(bcol + r) * DMODEL + k0 + sg * 8, lB + (i * 256 + w * 64) * 8);
    }
    __syncthreads();
    bf16x8 af[4], bfr[4];
#pragma unroll
    for (int m = 0; m < 4; ++m) af[m] = *(const bf16x8*)(lA + (wm * 64 + m * 16 + c) * 32 + qr * 8);
#pragma unroll
    for (int n = 0; n < 4; ++n) bfr[n] = *(const bf16x8*)(lB + (wn * 64 + n * 16 + c) * 32 + qr * 8);
#pragma unroll
    for (int m = 0; m < 4; ++m)
#pragma unroll
      for (int n = 0; n < 4; ++n)
        acc[m][n] = __builtin_amdgcn_mfma_f32_16x16x32_bf16(af[m], bfr[n], acc[m][n], 0, 0, 0);
    __syncthreads();
  }

  const int rb = qr * 4;
#pragma unroll
  for (int m = 0; m < 4; ++m) {
#pragma unroll
    for (int n = 0; n < 4; ++n) {
      f32x4 a = acc[m][n];
      int gm0 = brow + wm * 64 + m * 16 + rb;
      int gn = bcol + wn * 64 + n * 16 + c;
      if (mode == 3) {
        float* op = (float*)outp;
#pragma unroll
        for (int r = 0; r < 4; ++r) op[(size_t)(gm0 + r) * DMODEL + gn] = a[r];
      } else if (mode == 2) {
        u16* vt = (u16*)outp;
        int hh = gn >> 6, dh = gn & 63;
        int b = gm0 >> 11, s0 = gm0 & 2047;
        ushort4 pk;
        pk.x = f2bf(a[0]); pk.y = f2bf(a[1]); pk.z = f2bf(a[2]); pk.w = f2bf(a[3]);
        *reinterpret_cast<ushort4*>(vt + ((size_t)(b * NHEAD + hh) * DHEAD + dh) * S_LEN + s0) = pk;
      } else {
        u16* qk = (u16*)outp;
        float scale = (mode == 0) ? 0.125f : 1.0f;
        int hh = gn >> 6, dh = gn & 63;
#pragma unroll
        for (int r = 0; r < 4; ++r) {
          int gm = gm0 + r;
          int b = gm >> 11, s = gm & 2047;
          qk[((size_t)(b * NHEAD + hh) * S_LEN + s) * DHEAD + dh] = f2bf(a[r] * scale);
        }
      }
    }
  }
}

// Causal flash attention. Grid: (S/64, B*H). 256 threads = 4 waves; wave w owns q-rows
// [bx*64 + w*16, +16). KV tiles of 64. Q pre-scaled by 1/8. K/V LDS tiles XOR-swizzled
// (inverse swizzle applied on the global source of global_load_lds; swizzle on read).
__global__ __launch_bounds__(256) void attn_kernel(const u16* __restrict__ Q, const u16* __restrict__ K,
                                                   const u16* __restrict__ Vt, u16* __restrict__ O) {
  __shared__ u16 lsK[64 * 64];
  __shared__ u16 lsV[64 * 64];
  __shared__ u16 lsP[4][16 * 64];
  const int by = blockIdx.y;  // b*H + h
  const int bx = blockIdx.x;  // q tile
  const int tid = threadIdx.x;
  const int w = tid >> 6, lane = tid & 63;
  const int c = lane & 15, qr = lane >> 4;
  const int qb0 = bx * 64;
  const int q0 = qb0 + w * 16;

  bf16x8 aQ[2];
  const u16* qrow = Q + ((size_t)by * S_LEN + q0 + c) * DHEAD;
  aQ[0] = *(const bf16x8*)(qrow + qr * 8);
  aQ[1] = *(const bf16x8*)(qrow + 32 + qr * 8);

  f32x4 o_acc[4];
  float m_run[4], l_run[4];
#pragma unroll
  for (int d = 0; d < 4; ++d) o_acc[d] = (f32x4){0.f, 0.f, 0.f, 0.f};
#pragma unroll
  for (int r = 0; r < 4; ++r) { m_run[r] = -1e30f; l_run[r] = 0.f; }

  const int ntiles = bx + 1;
  for (int kt = 0; kt < ntiles; ++kt) {
    const int kv0 = kt * 64;
#pragma unroll
    for (int i = 0; i < 2; ++i) {
      int slot = i * 256 + w * 64 + lane;
      int r = slot >> 3, p = slot & 7;
      int ps = p ^ (r & 7);
      gld_lds16(K + ((size_t)by * S_LEN + kv0 + r) * DHEAD + ps * 8, lsK + (i * 256 + w * 64) * 8);
      gld_lds16(Vt + ((size_t)by * DHEAD + r) * S_LEN + kv0 + ps * 8, lsV + (i * 256 + w * 64) * 8);
    }
    __syncthreads();

    f32x4 sc[4];
#pragma unroll
    for (int nt = 0; nt < 4; ++nt) {
      int row = nt * 16 + c;
      const bf16x8 b0 = *(const bf16x8*)(lsK + row * 64 + ((qr ^ (row & 7)) * 8));
      const bf16x8 b1 = *(const bf16x8*)(lsK + row * 64 + (((4 + qr) ^ (row & 7)) * 8));
      f32x4 z = (f32x4){0.f, 0.f, 0.f, 0.f};
      z = __builtin_amdgcn_mfma_f32_16x16x32_bf16(aQ[0], b0, z, 0, 0, 0);
      z = __builtin_amdgcn_mfma_f32_16x16x32_bf16(aQ[1], b1, z, 0, 0, 0);
      sc[nt] = z;
    }
    if (kt == bx) {
#pragma unroll
      for (int nt = 0; nt < 4; ++nt)
#pragma unroll
        for (int r = 0; r < 4; ++r) {
          int col_g = kv0 + nt * 16 + c;
          int row_g = q0 + qr * 4 + r;
          if (col_g > row_g) sc[nt][r] = -1e30f;
        }
    }
#pragma unroll
    for (int r = 0; r < 4; ++r) {
      float tm = fmaxf(fmaxf(sc[0][r], sc[1][r]), fmaxf(sc[2][r], sc[3][r]));
#pragma unroll
      for (int sft = 1; sft < 16; sft <<= 1) tm = fmaxf(tm, __shfl_xor(tm, sft));
      float mn = fmaxf(m_run[r], tm);
      float al = __expf(m_run[r] - mn);
      m_run[r] = mn;
      float rs = 0.f;
#pragma unroll
      for (int nt = 0; nt < 4; ++nt) { float p = __expf(sc[nt][r] - mn); sc[nt][r] = p; rs += p; }
#pragma unroll
      for (int sft = 1; sft < 16; sft <<= 1) rs += __shfl_xor(rs, sft);
      l_run[r] = l_run[r] * al + rs;
#pragma unroll
      for (int d = 0; d < 4; ++d) o_acc[d][r] *= al;
    }
    u16* lp = lsP[w];
#pragma unroll
    for (int nt = 0; nt < 4; ++nt)
#pragma unroll
      for (int r = 0; r < 4; ++r) {
        int row = qr * 4 + r;
        int col = nt * 16 + c;
        int seg = col >> 3;
        lp[row * 64 + ((seg ^ (row & 7)) * 8) + (col & 7)] = f2bf(sc[nt][r]);
      }
    bf16x8 pa[2];
#pragma unroll
    for (int ks = 0; ks < 2; ++ks)
      pa[ks] = *(const bf16x8*)(lp + c * 64 + (((ks * 4 + qr) ^ (c & 7)) * 8));
#pragma unroll
    for (int dt = 0; dt < 4; ++dt) {
      int rowv = dt * 16 + c;
#pragma unroll
      for (int ks = 0; ks < 2; ++ks) {
        const bf16x8 vb = *(const bf16x8*)(lsV + rowv * 64 + (((ks * 4 + qr) ^ (rowv & 7)) * 8));
        o_acc[dt] = __builtin_amdgcn_mfma_f32_16x16x32_bf16(pa[ks], vb, o_acc[dt], 0, 0, 0);
      }
    }
    __syncthreads();
  }

  const int b = by >> 4, h = by & 15;
#pragma unroll
  for (int r = 0; r < 4; ++r) {
    float rl = 1.0f / l_run[r];
    int s = q0 + qr * 4 + r;
#pragma unroll
    for (int dt = 0; dt < 4; ++dt) {
      int dh = dt * 16 + c;
      O[(((size_t)b * S_LEN + s) * NHEAD + h) * DHEAD + dh] = f2bf(o_acc[dt][r] * rl);
    }
  }
}

extern "C" void kernel_launch(void* const* d_in, const int* in_sizes, int n_in,
                              void* d_out, int out_size, void* d_ws, size_t ws_size,
                              hipStream_t stream) {
  (void)in_sizes; (void)n_in; (void)out_size; (void)ws_size;
  const float* x  = (const float*)d_in[0];
  const float* Wq = (const float*)d_in[1];
  const float* Wk = (const float*)d_in[2];
  const float* Wv = (const float*)d_in[3];
  const float* Wo = (const float*)d_in[4];

  u16* ws  = (u16*)d_ws;
  u16* xb  = ws;                  // 8192*1024
  u16* wqb = xb  + 8388608;       // 1024*1024
  u16* wkb = wqb + 1048576;
  u16* wvb = wkb + 1048576;
  u16* wob = wvb + 1048576;
  u16* Qb  = wob + 1048576;       // [B][H][S][DH]
  u16* Kb  = Qb  + 8388608;
  u16* Vt  = Kb  + 8388608;       // [B*H][DH][S]
  u16* Ob  = Vt  + 8388608;       // [B][S][H][DH]

  cast_bf16_kernel<<<8192, 256, 0, stream>>>(x, xb, 2097152);
  cast_bf16_kernel<<<1024, 256, 0, stream>>>(Wq, wqb, 262144);
  cast_bf16_kernel<<<1024, 256, 0, stream>>>(Wk, wkb, 262144);
  cast_bf16_kernel<<<1024, 256, 0, stream>>>(Wv, wvb, 262144);
  cast_bf16_kernel<<<1024, 256, 0, stream>>>(Wo, wob, 262144);

  dim3 gg(8, 64);
  gemm_bt<<<gg, 256, 0, stream>>>(xb, wqb, Qb, 0);
  gemm_bt<<<gg, 256, 0, stream>>>(xb, wkb, Kb, 1);
  gemm_bt<<<gg, 256, 0, stream>>>(xb, wvb, Vt, 2);

  dim3 ga(32, 64);
  attn_kernel<<<ga, 256, 0, stream>>>(Qb, Kb, Vt, Ob);

  gemm_bt<<<gg, 256, 0, stream>>>(Ob, wob, (void*)d_out, 3);
}

// Round 2
// 232.564 us; speedup vs baseline: 1.6737x; 1.6737x over previous
//
#include <hip/hip_runtime.h>

typedef unsigned short u16;
typedef __attribute__((ext_vector_type(8))) short bf16x8;
typedef __attribute__((ext_vector_type(4))) short bf16x4;
typedef __attribute__((ext_vector_type(4))) float f32x4;

#define S_LEN 2048
#define NHEAD 16
#define DHEAD 64
#define DMODEL 1024
#define BATCH 4

__device__ __forceinline__ u16 f2bf(float f) {
  unsigned u = __builtin_bit_cast(unsigned, f);
  unsigned r = (u + 0x7fffu + ((u >> 16) & 1u)) >> 16;
  return (u16)r;
}

__device__ __forceinline__ void gld_lds16(const void* g, void* l) {
  __builtin_amdgcn_global_load_lds((const __attribute__((address_space(1))) unsigned*)g,
                                   (__attribute__((address_space(3))) unsigned*)l,
                                   16, 0, 0);
}

__global__ void cast_bf16_kernel(const float* __restrict__ in, u16* __restrict__ out, int n4) {
  int i = blockIdx.x * 256 + threadIdx.x;
  if (i >= n4) return;
  float4 v = reinterpret_cast<const float4*>(in)[i];
  ushort4 o;
  o.x = f2bf(v.x); o.y = f2bf(v.y); o.z = f2bf(v.z); o.w = f2bf(v.w);
  reinterpret_cast<ushort4*>(out)[i] = o;
}

// C = A (M x K) * B^T where B is (N x K) row-major. K = DMODEL = 1024. 128x128 tile, BK=32.
// mode 0: write Q bf16 [B][H][S][DH], scale 0.125 (1/sqrt(DH))
// mode 1: write K bf16 [B][H][S][DH]
// mode 2: write V bf16 transposed [B*H][DH][S]
// mode 3: write fp32 [M][N] row-major (final output projection)
__global__ __launch_bounds__(256) void gemm_bt(const u16* __restrict__ A, const u16* __restrict__ Bw,
                                               void* __restrict__ outp, int mode) {
  __shared__ u16 lA[128 * 32];
  __shared__ u16 lB[128 * 32];
  const int tid = threadIdx.x;
  const int w = tid >> 6, lane = tid & 63;
  const int wm = w >> 1, wn = w & 1;
  const int c = lane & 15, qr = lane >> 4;
  const int brow = blockIdx.y * 128;
  const int bcol = blockIdx.x * 128;
  f32x4 acc[4][4];
#pragma unroll
  for (int m = 0; m < 4; ++m)
#pragma unroll
    for (int n = 0; n < 4; ++n) acc[m][n] = (f32x4){0.f, 0.f, 0.f, 0.f};

  for (int kt = 0; kt < 32; ++kt) {
    const int k0 = kt * 32;
#pragma unroll
    for (int i = 0; i < 2; ++i) {
      int slot = i * 256 + w * 64 + lane;
      int r = slot >> 2, sg = slot & 3;
      gld_lds16(A + (size_t)(brow + r) * DMODEL + k0 + sg * 8, lA + (i * 256 + w * 64) * 8);
      gld_lds16(Bw + (size_t)(bcol + r) * DMODEL + k0 + sg * 8, lB + (i * 256 + w * 64) * 8);
    }
    __syncthreads();
    bf16x8 af[4], bfr[4];
#pragma unroll
    for (int m = 0; m < 4; ++m) af[m] = *(const bf16x8*)(lA + (wm * 64 + m * 16 + c) * 32 + qr * 8);
#pragma unroll
    for (int n = 0; n < 4; ++n) bfr[n] = *(const bf16x8*)(lB + (wn * 64 + n * 16 + c) * 32 + qr * 8);
#pragma unroll
    for (int m = 0; m < 4; ++m)
#pragma unroll
      for (int n = 0; n < 4; ++n)
        acc[m][n] = __builtin_amdgcn_mfma_f32_16x16x32_bf16(af[m], bfr[n], acc[m][n], 0, 0, 0);
    __syncthreads();
  }

  const int rb = qr * 4;
#pragma unroll
  for (int m = 0; m < 4; ++m) {
#pragma unroll
    for (int n = 0; n < 4; ++n) {
      f32x4 a = acc[m][n];
      int gm0 = brow + wm * 64 + m * 16 + rb;
      int gn = bcol + wn * 64 + n * 16 + c;
      if (mode == 3) {
        float* op = (float*)outp;
#pragma unroll
        for (int r = 0; r < 4; ++r) op[(size_t)(gm0 + r) * DMODEL + gn] = a[r];
      } else if (mode == 2) {
        u16* vt = (u16*)outp;
        int hh = gn >> 6, dh = gn & 63;
        int b = gm0 >> 11, s0 = gm0 & 2047;
        ushort4 pk;
        pk.x = f2bf(a[0]); pk.y = f2bf(a[1]); pk.z = f2bf(a[2]); pk.w = f2bf(a[3]);
        *reinterpret_cast<ushort4*>(vt + ((size_t)(b * NHEAD + hh) * DHEAD + dh) * S_LEN + s0) = pk;
      } else {
        u16* qk = (u16*)outp;
        float scale = (mode == 0) ? 0.125f : 1.0f;
        int hh = gn >> 6, dh = gn & 63;
#pragma unroll
        for (int r = 0; r < 4; ++r) {
          int gm = gm0 + r;
          int b = gm >> 11, s = gm & 2047;
          qk[((size_t)(b * NHEAD + hh) * S_LEN + s) * DHEAD + dh] = f2bf(a[r] * scale);
        }
      }
    }
  }
}

// Causal flash attention, swapped-operand form (lane-local k axis for softmax).
// Grid: (16, B*H). Block handles q-tiles {bx, 31-bx} (uniform 33 KV-tiles/block).
// 4 waves; wave w owns q-rows [qt*64 + w*16, +16). KV tiles of 64, double-buffered LDS.
// QK^T computed as mfma(K,Q) -> lane holds S[k=qr*4+r+16nt][q=c]; PV as mfma(Vt,P) -> O^T.
__global__ __launch_bounds__(256, 4) void attn_kernel(const u16* __restrict__ Q, const u16* __restrict__ K,
                                                      const u16* __restrict__ Vt, u16* __restrict__ O) {
  __shared__ u16 lsK[2][64 * 64];
  __shared__ u16 lsV[2][64 * 64];
  __shared__ u16 lsP[4][16 * 64];
  const int by = blockIdx.y;  // b*H + h
  const int bx = blockIdx.x;  // pair index
  const int tid = threadIdx.x;
  const int w = tid >> 6, lane = tid & 63;
  const int c = lane & 15, qr = lane >> 4;
  const int b = by >> 4, h = by & 15;
  u16* lp = lsP[w];

  for (int pass = 0; pass < 2; ++pass) {
    const int qt = pass ? (31 - bx) : bx;
    const int q0 = qt * 64 + w * 16;
    const u16* qrow = Q + ((size_t)by * S_LEN + q0 + c) * DHEAD;
    const bf16x8 aQ0 = *(const bf16x8*)(qrow + qr * 8);
    const bf16x8 aQ1 = *(const bf16x8*)(qrow + 32 + qr * 8);

    f32x4 o_acc[4];
#pragma unroll
    for (int d = 0; d < 4; ++d) o_acc[d] = (f32x4){0.f, 0.f, 0.f, 0.f};
    float m_run = -1e30f, l_run = 0.f;

    const int ntiles = qt + 1;
    // --- staging helper (inverse-swizzled global source, linear LDS dest) ---
    auto stage = [&](int kt, int buf) {
      const int kv0 = kt * 64;
#pragma unroll
      for (int i = 0; i < 2; ++i) {
        int slot = i * 256 + w * 64 + lane;
        int r = slot >> 3, p = slot & 7;
        int ps = p ^ (r & 7);
        gld_lds16(K + ((size_t)by * S_LEN + kv0 + r) * DHEAD + ps * 8, &lsK[buf][(i * 256 + w * 64) * 8]);
        gld_lds16(Vt + ((size_t)by * DHEAD + r) * S_LEN + kv0 + ps * 8, &lsV[buf][(i * 256 + w * 64) * 8]);
      }
    };

    stage(0, 0);
    __syncthreads();
    int cur = 0;
    for (int kt = 0; kt < ntiles; ++kt) {
      if (kt + 1 < ntiles) stage(kt + 1, cur ^ 1);  // issue early, drain at end barrier
      const int kv0 = kt * 64;
      const u16* bK = lsK[cur];
      const u16* bV = lsV[cur];

      f32x4 sc[4];
      __builtin_amdgcn_s_setprio(1);
#pragma unroll
      for (int nt = 0; nt < 4; ++nt) {
        int row = nt * 16 + c;
        const bf16x8 k0 = *(const bf16x8*)(bK + row * 64 + ((qr ^ (row & 7)) * 8));
        const bf16x8 k1 = *(const bf16x8*)(bK + row * 64 + (((4 + qr) ^ (row & 7)) * 8));
        f32x4 z = (f32x4){0.f, 0.f, 0.f, 0.f};
        z = __builtin_amdgcn_mfma_f32_16x16x32_bf16(k0, aQ0, z, 0, 0, 0);
        z = __builtin_amdgcn_mfma_f32_16x16x32_bf16(k1, aQ1, z, 0, 0, 0);
        sc[nt] = z;
      }
      __builtin_amdgcn_s_setprio(0);

      if (kt == qt) {  // diagonal tile: causal mask, k_g > q_g
#pragma unroll
        for (int nt = 0; nt < 4; ++nt)
#pragma unroll
          for (int r = 0; r < 4; ++r) {
            int k_g = kv0 + nt * 16 + qr * 4 + r;
            int q_g = q0 + c;
            if (k_g > q_g) sc[nt][r] = -1e30f;
          }
      }

      // --- lane-local softmax over k (16 regs) + 2-step cross-qr reduce ---
      float tm = fmaxf(fmaxf(fmaxf(sc[0][0], sc[0][1]), fmaxf(sc[0][2], sc[0][3])),
                       fmaxf(fmaxf(sc[1][0], sc[1][1]), fmaxf(sc[1][2], sc[1][3])));
      tm = fmaxf(tm, fmaxf(fmaxf(fmaxf(sc[2][0], sc[2][1]), fmaxf(sc[2][2], sc[2][3])),
                           fmaxf(fmaxf(sc[3][0], sc[3][1]), fmaxf(sc[3][2], sc[3][3]))));
      tm = fmaxf(tm, __shfl_xor(tm, 16));
      tm = fmaxf(tm, __shfl_xor(tm, 32));
      if (tm > m_run + 8.f) {  // defer-max (THR=8): rescale only on significant growth
        float al = __expf(m_run - tm);
        l_run *= al;
#pragma unroll
        for (int dt = 0; dt < 4; ++dt)
#pragma unroll
          for (int r = 0; r < 4; ++r) o_acc[dt][r] *= al;
        m_run = tm;
      }
      float rs = 0.f;
#pragma unroll
      for (int nt = 0; nt < 4; ++nt) {
        ushort4 pk;
#pragma unroll
        for (int r = 0; r < 4; ++r) {
          float p = __expf(sc[nt][r] - m_run);
          rs += p;
          ((u16*)&pk)[r] = f2bf(p);
        }
        // P[q=c][k_local group g=nt*4+qr], XOR-swizzled by c (8B granularity)
        *reinterpret_cast<ushort4*>(lp + c * 64 + (((nt * 4 + qr) ^ c) * 4)) = pk;
      }
      rs += __shfl_xor(rs, 16);
      rs += __shfl_xor(rs, 32);
      l_run += rs;

      // --- PV: O^T += Vt x P^T ---
      bf16x8 pb[2];
#pragma unroll
      for (int ks = 0; ks < 2; ++ks) {
        bf16x4 lo = *(const bf16x4*)(lp + c * 64 + (((ks * 8 + qr * 2) ^ c) * 4));
        bf16x4 hi = *(const bf16x4*)(lp + c * 64 + (((ks * 8 + qr * 2 + 1) ^ c) * 4));
        pb[ks] = (bf16x8){lo[0], lo[1], lo[2], lo[3], hi[0], hi[1], hi[2], hi[3]};
      }
      __builtin_amdgcn_s_setprio(1);
#pragma unroll
      for (int dt = 0; dt < 4; ++dt) {
        int rowv = dt * 16 + c;
#pragma unroll
        for (int ks = 0; ks < 2; ++ks) {
          const bf16x8 vb = *(const bf16x8*)(bV + rowv * 64 + (((ks * 4 + qr) ^ (rowv & 7)) * 8));
          o_acc[dt] = __builtin_amdgcn_mfma_f32_16x16x32_bf16(vb, pb[ks], o_acc[dt], 0, 0, 0);
        }
      }
      __builtin_amdgcn_s_setprio(0);
      __syncthreads();
      cur ^= 1;
    }

    // --- epilogue: lane holds O^T[d=dt*16+qr*4+r][q=c] ---
    float rl = 1.0f / l_run;
    int s = q0 + c;
#pragma unroll
    for (int dt = 0; dt < 4; ++dt) {
      ushort4 ok;
#pragma unroll
      for (int r = 0; r < 4; ++r) ((u16*)&ok)[r] = f2bf(o_acc[dt][r] * rl);
      *reinterpret_cast<ushort4*>(O + (((size_t)b * S_LEN + s) * NHEAD + h) * DHEAD + dt * 16 + qr * 4) = ok;
    }
  }
}

extern "C" void kernel_launch(void* const* d_in, const int* in_sizes, int n_in,
                              void* d_out, int out_size, void* d_ws, size_t ws_size,
                              hipStream_t stream) {
  (void)in_sizes; (void)n_in; (void)out_size; (void)ws_size;
  const float* x  = (const float*)d_in[0];
  const float* Wq = (const float*)d_in[1];
  const float* Wk = (const float*)d_in[2];
  const float* Wv = (const float*)d_in[3];
  const float* Wo = (const float*)d_in[4];

  u16* ws  = (u16*)d_ws;
  u16* xb  = ws;                  // 8192*1024
  u16* wqb = xb  + 8388608;       // 1024*1024
  u16* wkb = wqb + 1048576;
  u16* wvb = wkb + 1048576;
  u16* wob = wvb + 1048576;
  u16* Qb  = wob + 1048576;       // [B][H][S][DH]
  u16* Kb  = Qb  + 8388608;
  u16* Vt  = Kb  + 8388608;       // [B*H][DH][S]
  u16* Ob  = Vt  + 8388608;       // [B][S][H][DH]

  cast_bf16_kernel<<<8192, 256, 0, stream>>>(x, xb, 2097152);
  cast_bf16_kernel<<<1024, 256, 0, stream>>>(Wq, wqb, 262144);
  cast_bf16_kernel<<<1024, 256, 0, stream>>>(Wk, wkb, 262144);
  cast_bf16_kernel<<<1024, 256, 0, stream>>>(Wv, wvb, 262144);
  cast_bf16_kernel<<<1024, 256, 0, stream>>>(Wo, wob, 262144);

  dim3 gg(8, 64);
  gemm_bt<<<gg, 256, 0, stream>>>(xb, wqb, Qb, 0);
  gemm_bt<<<gg, 256, 0, stream>>>(xb, wkb, Kb, 1);
  gemm_bt<<<gg, 256, 0, stream>>>(xb, wvb, Vt, 2);

  dim3 ga(16, 64);
  attn_kernel<<<ga, 256, 0, stream>>>(Qb, Kb, Vt, Ob);

  gemm_bt<<<gg, 256, 0, stream>>>(Ob, wob, (void*)d_out, 3);
}

// Round 3
// 188.480 us; speedup vs baseline: 2.0652x; 1.2339x over previous
//
#include <hip/hip_runtime.h>

typedef unsigned short u16;
typedef __attribute__((ext_vector_type(8))) short bf16x8;
typedef __attribute__((ext_vector_type(4))) short bf16x4;
typedef __attribute__((ext_vector_type(4))) float f32x4;

#define S_LEN 2048
#define NHEAD 16
#define DHEAD 64
#define DMODEL 1024

__device__ __forceinline__ u16 f2bf(float f) {
  unsigned u = __builtin_bit_cast(unsigned, f);
  unsigned r = (u + 0x7fffu + ((u >> 16) & 1u)) >> 16;
  return (u16)r;
}

__device__ __forceinline__ void gld_lds16(const void* g, void* l) {
  __builtin_amdgcn_global_load_lds((const __attribute__((address_space(1))) unsigned*)g,
                                   (__attribute__((address_space(3))) unsigned*)l,
                                   16, 0, 0);
}

__global__ void cast_bf16_kernel(const float* __restrict__ in, u16* __restrict__ out, int n4) {
  int i = blockIdx.x * 256 + threadIdx.x;
  if (i >= n4) return;
  float4 v = reinterpret_cast<const float4*>(in)[i];
  ushort4 o;
  o.x = f2bf(v.x); o.y = f2bf(v.y); o.z = f2bf(v.z); o.w = f2bf(v.w);
  reinterpret_cast<ushort4*>(out)[i] = o;
}

// Cast Wq,Wk,Wv,Wo (each 1024x1024 fp32) into one contiguous bf16 block [Wq;Wk;Wv;Wo].
__global__ void cast_w_kernel(const float* __restrict__ Wq, const float* __restrict__ Wk,
                              const float* __restrict__ Wv, const float* __restrict__ Wo,
                              u16* __restrict__ out) {
  int id = blockIdx.x * 256 + threadIdx.x;  // over 1048576 float4 groups
  int wsel = id >> 18, j = id & 262143;     // block-uniform wsel (1024 blocks per weight)
  const float* s = wsel < 2 ? (wsel == 0 ? Wq : Wk) : (wsel == 2 ? Wv : Wo);
  float4 v = reinterpret_cast<const float4*>(s)[j];
  ushort4 o;
  o.x = f2bf(v.x); o.y = f2bf(v.y); o.z = f2bf(v.z); o.w = f2bf(v.w);
  reinterpret_cast<ushort4*>(out)[id] = o;
}

// C = A (8192 x 1024) * B^T, B row-major (N x 1024). 128x128 tile, BK=32, 2-phase dbuf.
// Grid is 1D, XCD-swizzled: xcd=hw&7 -> by in [8*xcd, 8*xcd+8) (A panels L2-resident/XCD).
// mode 4: N=3072 fused QKV epilogue. outp=Qb; Kb=Qb+8M, Vt=Kb+8M.
//         cols [0,1024): Q scaled by 0.125*log2(e), scatter [B][H][S][DH]
//         cols [1024,2048): K scatter [B][H][S][DH]
//         cols [2048,3072): V transposed [B*H][DH][S] (ushort4 along s)
// mode 3: N=1024, fp32 row-major [8192][1024] (final projection)
__global__ __launch_bounds__(256) void gemm_bt(const u16* __restrict__ A, const u16* __restrict__ Bw,
                                               void* __restrict__ outp, int mode) {
  __shared__ u16 lA[2][128 * 32];
  __shared__ u16 lB[2][128 * 32];
  const int hw = blockIdx.x;
  const int xcd = hw & 7, vv = hw >> 3;
  const int bx = vv >> 3, by = xcd * 8 + (vv & 7);
  const int tid = threadIdx.x;
  const int w = tid >> 6, lane = tid & 63;
  const int wm = w >> 1, wn = w & 1;
  const int c = lane & 15, qr = lane >> 4;
  const int brow = by * 128, bcol = bx * 128;
  f32x4 acc[4][4];
#pragma unroll
  for (int m = 0; m < 4; ++m)
#pragma unroll
    for (int n = 0; n < 4; ++n) acc[m][n] = (f32x4){0.f, 0.f, 0.f, 0.f};

  auto stage = [&](int kt, int bsel) {
    const int k0 = kt * 32;
#pragma unroll
    for (int i = 0; i < 2; ++i) {
      int slot = i * 256 + w * 64 + lane;
      int r = slot >> 2, sg = slot & 3;
      gld_lds16(A + (size_t)(brow + r) * DMODEL + k0 + sg * 8, &lA[bsel][(i * 256 + w * 64) * 8]);
      gld_lds16(Bw + (size_t)(bcol + r) * DMODEL + k0 + sg * 8, &lB[bsel][(i * 256 + w * 64) * 8]);
    }
  };

  stage(0, 0);
  __syncthreads();
  int cur = 0;
  for (int kt = 0; kt < 32; ++kt) {
    if (kt < 31) stage(kt + 1, cur ^ 1);  // prefetch next tile into other buffer
    bf16x8 af[4], bfr[4];
#pragma unroll
    for (int m = 0; m < 4; ++m) af[m] = *(const bf16x8*)(&lA[cur][(wm * 64 + m * 16 + c) * 32 + qr * 8]);
#pragma unroll
    for (int n = 0; n < 4; ++n) bfr[n] = *(const bf16x8*)(&lB[cur][(wn * 64 + n * 16 + c) * 32 + qr * 8]);
    __builtin_amdgcn_s_setprio(1);
#pragma unroll
    for (int m = 0; m < 4; ++m)
#pragma unroll
      for (int n = 0; n < 4; ++n)
        acc[m][n] = __builtin_amdgcn_mfma_f32_16x16x32_bf16(af[m], bfr[n], acc[m][n], 0, 0, 0);
    __builtin_amdgcn_s_setprio(0);
    __syncthreads();
    cur ^= 1;
  }

  const int rb = qr * 4;
#pragma unroll
  for (int m = 0; m < 4; ++m) {
#pragma unroll
    for (int n = 0; n < 4; ++n) {
      f32x4 a = acc[m][n];
      int gm0 = brow + wm * 64 + m * 16 + rb;
      int gn = bcol + wn * 64 + n * 16 + c;
      if (mode == 3) {
        float* op = (float*)outp;
#pragma unroll
        for (int r = 0; r < 4; ++r) op[(size_t)(gm0 + r) * DMODEL + gn] = a[r];
      } else {
        u16* Qb = (u16*)outp;
        u16* Kb = Qb + 8388608;
        u16* Vt = Kb + 8388608;
        int mat = gn >> 10, gl = gn & 1023;
        int hh = gl >> 6, dh = gl & 63;
        int b = gm0 >> 11;
        if (mat == 2) {  // V transposed
          int s0 = gm0 & 2047;
          ushort4 pk;
          pk.x = f2bf(a[0]); pk.y = f2bf(a[1]); pk.z = f2bf(a[2]); pk.w = f2bf(a[3]);
          *reinterpret_cast<ushort4*>(Vt + ((size_t)(b * NHEAD + hh) * DHEAD + dh) * S_LEN + (s0)) = pk;
        } else {
          // Q carries 1/sqrt(DH) * log2(e) so attention softmax runs in exp2 domain
          float scale = (mat == 0) ? 0.1803368801111204f : 1.0f;
          u16* dst = (mat == 0) ? Qb : Kb;
#pragma unroll
          for (int r = 0; r < 4; ++r) {
            int gm = gm0 + r;
            int s = gm & 2047;
            dst[((size_t)(b * NHEAD + hh) * S_LEN + s) * DHEAD + dh] = f2bf(a[r] * scale);
          }
        }
      }
    }
  }
}

// Causal flash attention, swapped-operand, QBLK=128, merged causal pair (j, 15-j).
// Grid: 512 blocks x 512 threads (8 waves). XCD swizzle groups all 8 j-blocks of a
// (b,h) on one XCD so K/V (512KB) stay L2-resident. KV tiles of 64, dbuf LDS staged
// once for the pair's union. Wave w owns q-rows [qt*128 + w*16, +16) of each sub-tile.
__global__ __launch_bounds__(512, 4) void attn_kernel(const u16* __restrict__ Q, const u16* __restrict__ K,
                                                      const u16* __restrict__ Vt, u16* __restrict__ O) {
  __shared__ u16 lsK[2][64 * 64];
  __shared__ u16 lsV[2][64 * 64];
  __shared__ u16 lsP[8][16 * 64];
  const int hw = blockIdx.x;
  const int xcd = hw & 7, vv = hw >> 3;   // vv in [0,64)
  const int by = xcd * 8 + (vv >> 3);     // (b*16+h), grouped per XCD
  const int j = vv & 7;                   // pair (j, 15-j) of 128-row q-tiles
  const int tid = threadIdx.x;
  const int w = tid >> 6, lane = tid & 63;
  const int c = lane & 15, qr = lane >> 4;
  const int b = by >> 4, h = by & 15;
  u16* lp = lsP[w];

  const int q0A = j * 128 + w * 16;
  const int q0B = (15 - j) * 128 + w * 16;
  const int ndA = q0A >> 6, ndB = q0B >> 6;  // diagonal kv-tile per wave
  const int ntiles = 32 - 2 * j;             // staged union = 0..(2*(15-j)+1)

  const u16* qra = Q + ((size_t)by * S_LEN + q0A + c) * DHEAD;
  const u16* qrb = Q + ((size_t)by * S_LEN + q0B + c) * DHEAD;
  const bf16x8 aQA0 = *(const bf16x8*)(qra + qr * 8);
  const bf16x8 aQA1 = *(const bf16x8*)(qra + 32 + qr * 8);
  const bf16x8 aQB0 = *(const bf16x8*)(qrb + qr * 8);
  const bf16x8 aQB1 = *(const bf16x8*)(qrb + 32 + qr * 8);

  f32x4 oA[4], oB[4];
#pragma unroll
  for (int d = 0; d < 4; ++d) { oA[d] = (f32x4){0.f, 0.f, 0.f, 0.f}; oB[d] = oA[d]; }
  float mA = -1e30f, lA_ = 0.f, mB = -1e30f, lB_ = 0.f;

  auto stage = [&](int kt, int bsel) {  // 512 threads: 1 gld_lds per matrix per thread
    const int kv0 = kt * 64;
    int r = tid >> 3, p = tid & 7;
    int ps = p ^ (r & 7);  // inverse swizzle on global source, linear LDS dest
    gld_lds16(K + ((size_t)by * S_LEN + kv0 + r) * DHEAD + ps * 8, &lsK[bsel][(w * 64) * 8]);
    gld_lds16(Vt + ((size_t)by * DHEAD + r) * S_LEN + kv0 + ps * 8, &lsV[bsel][(w * 64) * 8]);
  };

  auto process = [&](const u16* bK, const u16* bV, int kt, int nd, int q0,
                     const bf16x8& aQ0, const bf16x8& aQ1,
                     f32x4* o_acc, float& m_run, float& l_run) {
    const int kv0 = kt * 64;
    f32x4 sc[4];
    __builtin_amdgcn_s_setprio(1);
#pragma unroll
    for (int nt = 0; nt < 4; ++nt) {
      int row = nt * 16 + c;
      const bf16x8 k0 = *(const bf16x8*)(bK + row * 64 + ((qr ^ (row & 7)) * 8));
      const bf16x8 k1 = *(const bf16x8*)(bK + row * 64 + (((4 + qr) ^ (row & 7)) * 8));
      f32x4 z = (f32x4){0.f, 0.f, 0.f, 0.f};
      z = __builtin_amdgcn_mfma_f32_16x16x32_bf16(k0, aQ0, z, 0, 0, 0);
      z = __builtin_amdgcn_mfma_f32_16x16x32_bf16(k1, aQ1, z, 0, 0, 0);
      sc[nt] = z;
    }
    __builtin_amdgcn_s_setprio(0);

    if (kt == nd) {  // causal mask on diagonal tile
#pragma unroll
      for (int nt = 0; nt < 4; ++nt)
#pragma unroll
        for (int r = 0; r < 4; ++r) {
          int k_g = kv0 + nt * 16 + qr * 4 + r;
          int q_g = q0 + c;
          if (k_g > q_g) sc[nt][r] = -1e30f;
        }
    }

    // lane-local max over 16 k's + 2-step cross-qr reduce (scores are in log2 domain)
    float tm = fmaxf(fmaxf(fmaxf(sc[0][0], sc[0][1]), fmaxf(sc[0][2], sc[0][3])),
                     fmaxf(fmaxf(sc[1][0], sc[1][1]), fmaxf(sc[1][2], sc[1][3])));
    tm = fmaxf(tm, fmaxf(fmaxf(fmaxf(sc[2][0], sc[2][1]), fmaxf(sc[2][2], sc[2][3])),
                         fmaxf(fmaxf(sc[3][0], sc[3][1]), fmaxf(sc[3][2], sc[3][3]))));
    tm = fmaxf(tm, __shfl_xor(tm, 16));
    tm = fmaxf(tm, __shfl_xor(tm, 32));
    if (tm > m_run + 11.5f) {  // defer-max (11.5 bits ~ e^8)
      float al = __builtin_amdgcn_exp2f(m_run - tm);
      l_run *= al;
#pragma unroll
      for (int dt = 0; dt < 4; ++dt)
#pragma unroll
        for (int r = 0; r < 4; ++r) o_acc[dt][r] *= al;
      m_run = tm;
    }
    float rs = 0.f;
#pragma unroll
    for (int nt = 0; nt < 4; ++nt) {
      ushort4 pk;
#pragma unroll
      for (int r = 0; r < 4; ++r) {
        float p = __builtin_amdgcn_exp2f(sc[nt][r] - m_run);
        rs += p;
        ((u16*)&pk)[r] = f2bf(p);
      }
      *reinterpret_cast<ushort4*>(lp + c * 64 + (((nt * 4 + qr) ^ c) * 4)) = pk;
    }
    rs += __shfl_xor(rs, 16);
    rs += __shfl_xor(rs, 32);
    l_run += rs;

    bf16x8 pb[2];
#pragma unroll
    for (int ks = 0; ks < 2; ++ks) {
      bf16x4 lo = *(const bf16x4*)(lp + c * 64 + (((ks * 8 + qr * 2) ^ c) * 4));
      bf16x4 hi = *(const bf16x4*)(lp + c * 64 + (((ks * 8 + qr * 2 + 1) ^ c) * 4));
      pb[ks] = (bf16x8){lo[0], lo[1], lo[2], lo[3], hi[0], hi[1], hi[2], hi[3]};
    }
    __builtin_amdgcn_s_setprio(1);
#pragma unroll
    for (int dt = 0; dt < 4; ++dt) {
      int rowv = dt * 16 + c;
#pragma unroll
      for (int ks = 0; ks < 2; ++ks) {
        const bf16x8 vb = *(const bf16x8*)(bV + rowv * 64 + (((ks * 4 + qr) ^ (rowv & 7)) * 8));
        o_acc[dt] = __builtin_amdgcn_mfma_f32_16x16x32_bf16(vb, pb[ks], o_acc[dt], 0, 0, 0);
      }
    }
    __builtin_amdgcn_s_setprio(0);
  };

  stage(0, 0);
  __syncthreads();
  int cur = 0;
  for (int kt = 0; kt < ntiles; ++kt) {
    if (kt + 1 < ntiles) stage(kt + 1, cur ^ 1);
    if (kt <= ndB) process(lsK[cur], lsV[cur], kt, ndB, q0B, aQB0, aQB1, oB, mB, lB_);
    if (kt <= ndA) process(lsK[cur], lsV[cur], kt, ndA, q0A, aQA0, aQA1, oA, mA, lA_);
    __syncthreads();
    cur ^= 1;
  }

  // epilogue: lane holds O^T[d = dt*16+qr*4+r][q = c] per sub-tile
  {
    float rl = 1.0f / lB_;
    int s = q0B + c;
#pragma unroll
    for (int dt = 0; dt < 4; ++dt) {
      ushort4 ok;
#pragma unroll
      for (int r = 0; r < 4; ++r) ((u16*)&ok)[r] = f2bf(oB[dt][r] * rl);
      *reinterpret_cast<ushort4*>(O + (((size_t)b * S_LEN + s) * NHEAD + h) * DHEAD + dt * 16 + qr * 4) = ok;
    }
  }
  {
    float rl = 1.0f / lA_;
    int s = q0A + c;
#pragma unroll
    for (int dt = 0; dt < 4; ++dt) {
      ushort4 ok;
#pragma unroll
      for (int r = 0; r < 4; ++r) ((u16*)&ok)[r] = f2bf(oA[dt][r] * rl);
      *reinterpret_cast<ushort4*>(O + (((size_t)b * S_LEN + s) * NHEAD + h) * DHEAD + dt * 16 + qr * 4) = ok;
    }
  }
}

extern "C" void kernel_launch(void* const* d_in, const int* in_sizes, int n_in,
                              void* d_out, int out_size, void* d_ws, size_t ws_size,
                              hipStream_t stream) {
  (void)in_sizes; (void)n_in; (void)out_size; (void)ws_size;
  const float* x  = (const float*)d_in[0];
  const float* Wq = (const float*)d_in[1];
  const float* Wk = (const float*)d_in[2];
  const float* Wv = (const float*)d_in[3];
  const float* Wo = (const float*)d_in[4];

  u16* ws  = (u16*)d_ws;
  u16* xb  = ws;                  // 8192*1024
  u16* wqb = xb  + 8388608;       // [Wq;Wk;Wv;Wo] contiguous, 4*1024*1024
  u16* wob = wqb + 3145728;
  u16* Qb  = wqb + 4194304;       // [B][H][S][DH]  (scaled by 0.125*log2e)
  u16* Kb  = Qb  + 8388608;       // [B][H][S][DH]
  u16* Vt  = Kb  + 8388608;       // [B*H][DH][S]
  u16* Ob  = Vt  + 8388608;       // [B][S][H][DH]

  cast_bf16_kernel<<<8192, 256, 0, stream>>>(x, xb, 2097152);
  cast_w_kernel<<<4096, 256, 0, stream>>>(Wq, Wk, Wv, Wo, wqb);

  gemm_bt<<<1536, 256, 0, stream>>>(xb, wqb, Qb, 4);   // fused QKV
  attn_kernel<<<512, 512, 0, stream>>>(Qb, Kb, Vt, Ob);
  gemm_bt<<<512, 256, 0, stream>>>(Ob, wob, (void*)d_out, 3);
}

// Round 4
// 183.576 us; speedup vs baseline: 2.1204x; 1.0267x over previous
//
#include <hip/hip_runtime.h>

typedef unsigned short u16;
typedef unsigned int u32;
typedef __attribute__((ext_vector_type(8))) short bf16x8;
typedef __attribute__((ext_vector_type(4))) short bf16x4;
typedef __attribute__((ext_vector_type(4))) float f32x4;

#define S_LEN 2048
#define NHEAD 16
#define DHEAD 64
#define DMODEL 1024

__device__ __forceinline__ u16 f2bf(float f) {
  unsigned u = __builtin_bit_cast(unsigned, f);
  unsigned r = (u + 0x7fffu + ((u >> 16) & 1u)) >> 16;
  return (u16)r;
}

__device__ __forceinline__ void gld_lds16(const void* g, void* l) {
  __builtin_amdgcn_global_load_lds((const __attribute__((address_space(1))) unsigned*)g,
                                   (__attribute__((address_space(3))) unsigned*)l,
                                   16, 0, 0);
}

__global__ void cast_bf16_kernel(const float* __restrict__ in, u16* __restrict__ out, int n4) {
  int i = blockIdx.x * 256 + threadIdx.x;
  if (i >= n4) return;
  float4 v = reinterpret_cast<const float4*>(in)[i];
  ushort4 o;
  o.x = f2bf(v.x); o.y = f2bf(v.y); o.z = f2bf(v.z); o.w = f2bf(v.w);
  reinterpret_cast<ushort4*>(out)[i] = o;
}

__global__ void cast_w_kernel(const float* __restrict__ Wq, const float* __restrict__ Wk,
                              const float* __restrict__ Wv, const float* __restrict__ Wo,
                              u16* __restrict__ out) {
  int id = blockIdx.x * 256 + threadIdx.x;
  int wsel = id >> 18, j = id & 262143;
  const float* s = wsel < 2 ? (wsel == 0 ? Wq : Wk) : (wsel == 2 ? Wv : Wo);
  float4 v = reinterpret_cast<const float4*>(s)[j];
  ushort4 o;
  o.x = f2bf(v.x); o.y = f2bf(v.y); o.z = f2bf(v.z); o.w = f2bf(v.w);
  reinterpret_cast<ushort4*>(out)[id] = o;
}

// ------------------- fused QKV GEMM: 256x256 tile, BK=64, 8-phase schedule -------------------
// C = A(8192x1024) * B^T (B = [Wq;Wk;Wv] 3072x1024). 512 thr = 8 waves (2M x 4N), per-wave 128x64.
// LDS 128KiB: [buf2][A,B][half2][128][64] bf16, st_16x32 swizzle (byte ^= ((byte>>9)&1)<<5) applied
// via inverse-swizzled global source (stage) + swizzled ds_read (read) — rule #21 both-sides.
// vmcnt(6) only at phases 4/8 (counted, never 0 mid-loop). Epilogue scatters Q(scaled)/K/V^T.
#define MFMA_Q(mlo, nlo)                                                                     \
  _Pragma("unroll") for (int m_ = 0; m_ < 4; ++m_)                                           \
  _Pragma("unroll") for (int n_ = 0; n_ < 2; ++n_)                                           \
  _Pragma("unroll") for (int kk_ = 0; kk_ < 2; ++kk_)                                        \
    acc[(mlo) + m_][(nlo) + n_] = __builtin_amdgcn_mfma_f32_16x16x32_bf16(                   \
        af[(mlo) + m_][kk_], bf[(nlo) + n_][kk_], acc[(mlo) + m_][(nlo) + n_], 0, 0, 0);

#define VM6 do { __builtin_amdgcn_sched_barrier(0);                                          \
  asm volatile("s_waitcnt vmcnt(6)" ::: "memory");                                           \
  __builtin_amdgcn_sched_barrier(0); } while (0)
#define VM0 do { __builtin_amdgcn_sched_barrier(0);                                          \
  asm volatile("s_waitcnt vmcnt(0)" ::: "memory");                                           \
  __builtin_amdgcn_sched_barrier(0); } while (0)

#define HALF_ITER(bb, S1, S2, S3, S4, WAIT) do {                                             \
  const u16* aB = aB0 + (bb)*32768;                                                          \
  const u16* bB = bB0 + (bb)*32768;                                                          \
  /* P1 */                                                                                   \
  _Pragma("unroll") for (int m_ = 0; m_ < 4; ++m_) {                                         \
    af[m_][0] = rdA(aB, m_, 0); af[m_][1] = rdA(aB, m_, 1); }                                \
  _Pragma("unroll") for (int n_ = 0; n_ < 2; ++n_) {                                         \
    bf[n_][0] = rdB(bB, n_, 0); bf[n_][1] = rdB(bB, n_, 1); }                                \
  S1;                                                                                        \
  __builtin_amdgcn_s_barrier();                                                              \
  __builtin_amdgcn_s_setprio(1); MFMA_Q(0, 0) __builtin_amdgcn_s_setprio(0);                 \
  __builtin_amdgcn_s_barrier();                                                              \
  /* P2 */                                                                                   \
  _Pragma("unroll") for (int m_ = 0; m_ < 4; ++m_) {                                         \
    af[4 + m_][0] = rdA(aB, 4 + m_, 0); af[4 + m_][1] = rdA(aB, 4 + m_, 1); }                \
  S2;                                                                                        \
  __builtin_amdgcn_s_barrier();                                                              \
  __builtin_amdgcn_s_setprio(1); MFMA_Q(4, 0) __builtin_amdgcn_s_setprio(0);                 \
  __builtin_amdgcn_s_barrier();                                                              \
  /* P3 */                                                                                   \
  _Pragma("unroll") for (int n_ = 0; n_ < 2; ++n_) {                                         \
    bf[2 + n_][0] = rdB(bB, 2 + n_, 0); bf[2 + n_][1] = rdB(bB, 2 + n_, 1); }                \
  S3;                                                                                        \
  __builtin_amdgcn_s_barrier();                                                              \
  __builtin_amdgcn_s_setprio(1); MFMA_Q(0, 2) __builtin_amdgcn_s_setprio(0);                 \
  __builtin_amdgcn_s_barrier();                                                              \
  /* P4 */                                                                                   \
  S4;                                                                                        \
  __builtin_amdgcn_s_barrier();                                                              \
  __builtin_amdgcn_s_setprio(1); MFMA_Q(4, 2) __builtin_amdgcn_s_setprio(0);                 \
  WAIT;                                                                                      \
  __builtin_amdgcn_s_barrier();                                                              \
} while (0)

__global__ __launch_bounds__(512, 2) void gemm_qkv(const u16* __restrict__ A,
                                                   const u16* __restrict__ Bw,
                                                   u16* __restrict__ Qb) {
  __shared__ u16 lds[65536];  // 128 KiB
  const int bid = blockIdx.x;
  const int xcd = bid & 7, v = bid >> 3;           // 48 blocks / XCD (384 % 8 == 0, bijective)
  const int by = xcd * 4 + (v & 3), bx = v >> 2;   // by 0..31 (M), bx 0..11 (N)
  const int brow = by * 256, bcol = bx * 256;
  const int tid = threadIdx.x;
  const int w = tid >> 6, lane = tid & 63;
  const int wm = w >> 2, wn = w & 3;
  const int c = lane & 15, qr = lane >> 4;
  const int sq = (qr * 8) ^ (((c >> 2) & 1) << 4);  // swizzled k-offset (u16 units)

  auto stg = [&](int mat, int tau, int half) {
    if (tau >= 16) return;
    u16* region = lds + (tau & 1) * 32768 + mat * 16384 + half * 8192;
    const u16* G = mat ? Bw : A;
    int rowb = (mat ? bcol : brow) + half * 128;
    int k0 = tau * 64;
#pragma unroll
    for (int i = 0; i < 2; ++i) {
      int slot = i * 512 + tid;
      int r = slot >> 3, cb = slot & 7;
      int cbs = cb ^ (((r >> 2) & 1) << 1);  // inverse st_16x32 swizzle on global source
      gld_lds16(G + (size_t)(rowb + r) * DMODEL + k0 + cbs * 8, region + (i * 512 + w * 64) * 8);
    }
  };

  auto rdA = [&](const u16* base, int m, int kk) {
    return *(const bf16x8*)(base + (m * 16 + c) * 64 + kk * 32 + sq);
  };
  auto rdB = [&](const u16* base, int n, int kk) {
    return *(const bf16x8*)(base + ((wn & 1) * 64 + n * 16 + c) * 64 + kk * 32 + sq);
  };

  f32x4 acc[8][4];
#pragma unroll
  for (int m = 0; m < 8; ++m)
#pragma unroll
    for (int n = 0; n < 4; ++n) acc[m][n] = (f32x4){0.f, 0.f, 0.f, 0.f};
  bf16x8 af[8][2], bf[4][2];
  const u16* aB0 = lds + wm * 8192;
  const u16* bB0 = lds + 16384 + (wn >> 1) * 8192;

  // prologue: T0 complete + T1 {A0,A1,B0}; wait oldest 8 loads (= T0)
  stg(0, 0, 0); stg(0, 0, 1); stg(1, 0, 0); stg(1, 0, 1);
  stg(0, 1, 0); stg(0, 1, 1); stg(1, 1, 0);
  VM6;
  __builtin_amdgcn_s_barrier();

#pragma unroll 1
  for (int t = 0; t < 8; ++t) {
    const int e = 2 * t;
    // phases 1-4: K-tile e (buf0); stage (e+1).B1, (e+2).{A0,A1,B0}
    HALF_ITER(0,
              stg(1, e + 1, 1),
              stg(0, e + 2, 0),
              stg(0, e + 2, 1),
              stg(1, e + 2, 0),
              if (t < 7) { VM6; } else { VM0; });
    // phases 5-8: K-tile e+1 (buf1); stage (e+2).B1, (e+3).{A0,A1,B0}
    HALF_ITER(1,
              stg(1, e + 2, 1),
              stg(0, e + 3, 0),
              stg(0, e + 3, 1),
              stg(1, e + 3, 0),
              if (t < 7) { VM6; });
  }

  // epilogue: scatter Q (scaled, exp2-domain), K, V^T
  u16* Kb = Qb + 8388608;
  u16* Vt = Kb + 8388608;
#pragma unroll
  for (int m = 0; m < 8; ++m) {
#pragma unroll
    for (int n = 0; n < 4; ++n) {
      f32x4 a = acc[m][n];
      int gm0 = brow + wm * 128 + m * 16 + qr * 4;
      int gn = bcol + wn * 64 + n * 16 + c;
      int mat = gn >> 10, gl = gn & 1023;
      int hh = gl >> 6, dh = gl & 63;
      int b = gm0 >> 11;
      if (mat == 2) {  // V transposed: [B*H][DH][S], 4 consecutive s
        int s0 = gm0 & 2047;
        ushort4 pk;
        pk.x = f2bf(a[0]); pk.y = f2bf(a[1]); pk.z = f2bf(a[2]); pk.w = f2bf(a[3]);
        *reinterpret_cast<ushort4*>(Vt + ((size_t)(b * NHEAD + hh) * DHEAD + dh) * S_LEN + s0) = pk;
      } else {
        float scale = (mat == 0) ? 0.1803368801111204f : 1.0f;  // 0.125 * log2(e) for Q
        u16* dst = (mat == 0) ? Qb : Kb;
#pragma unroll
        for (int r = 0; r < 4; ++r) {
          int gm = gm0 + r;
          int s = gm & 2047;
          dst[((size_t)(b * NHEAD + hh) * S_LEN + s) * DHEAD + dh] = f2bf(a[r] * scale);
        }
      }
    }
  }
}

// ------------------- AO projection: 128x128 tile, BK=32, 2-phase dbuf -------------------
__global__ __launch_bounds__(256) void gemm_bt(const u16* __restrict__ A, const u16* __restrict__ Bw,
                                               float* __restrict__ outp) {
  __shared__ u16 lA[2][128 * 32];
  __shared__ u16 lB[2][128 * 32];
  const int hw = blockIdx.x;
  const int xcd = hw & 7, vv = hw >> 3;
  const int bx = vv >> 3, by = xcd * 8 + (vv & 7);
  const int tid = threadIdx.x;
  const int w = tid >> 6, lane = tid & 63;
  const int wm = w >> 1, wn = w & 1;
  const int c = lane & 15, qr = lane >> 4;
  const int brow = by * 128, bcol = bx * 128;
  f32x4 acc[4][4];
#pragma unroll
  for (int m = 0; m < 4; ++m)
#pragma unroll
    for (int n = 0; n < 4; ++n) acc[m][n] = (f32x4){0.f, 0.f, 0.f, 0.f};

  auto stage = [&](int kt, int bsel) {
    const int k0 = kt * 32;
#pragma unroll
    for (int i = 0; i < 2; ++i) {
      int slot = i * 256 + w * 64 + lane;
      int r = slot >> 2, sg = slot & 3;
      gld_lds16(A + (size_t)(brow + r) * DMODEL + k0 + sg * 8, &lA[bsel][(i * 256 + w * 64) * 8]);
      gld_lds16(Bw + (size_t)(bcol + r) * DMODEL + k0 + sg * 8, &lB[bsel][(i * 256 + w * 64) * 8]);
    }
  };

  stage(0, 0);
  __syncthreads();
  int cur = 0;
  for (int kt = 0; kt < 32; ++kt) {
    if (kt < 31) stage(kt + 1, cur ^ 1);
    bf16x8 af[4], bfr[4];
#pragma unroll
    for (int m = 0; m < 4; ++m) af[m] = *(const bf16x8*)(&lA[cur][(wm * 64 + m * 16 + c) * 32 + qr * 8]);
#pragma unroll
    for (int n = 0; n < 4; ++n) bfr[n] = *(const bf16x8*)(&lB[cur][(wn * 64 + n * 16 + c) * 32 + qr * 8]);
    __builtin_amdgcn_s_setprio(1);
#pragma unroll
    for (int m = 0; m < 4; ++m)
#pragma unroll
      for (int n = 0; n < 4; ++n)
        acc[m][n] = __builtin_amdgcn_mfma_f32_16x16x32_bf16(af[m], bfr[n], acc[m][n], 0, 0, 0);
    __builtin_amdgcn_s_setprio(0);
    __syncthreads();
    cur ^= 1;
  }

  const int rb = qr * 4;
#pragma unroll
  for (int m = 0; m < 4; ++m)
#pragma unroll
    for (int n = 0; n < 4; ++n) {
      f32x4 a = acc[m][n];
      int gm0 = brow + wm * 64 + m * 16 + rb;
      int gn = bcol + wn * 64 + n * 16 + c;
#pragma unroll
      for (int r = 0; r < 4; ++r) outp[(size_t)(gm0 + r) * DMODEL + gn] = a[r];
    }
}

// ------------------- causal flash attention (swapped operands, exp2 domain) -------------------
__global__ __launch_bounds__(512, 4) void attn_kernel(const u16* __restrict__ Q, const u16* __restrict__ K,
                                                      const u16* __restrict__ Vt, u16* __restrict__ O) {
  __shared__ u16 lsK[2][64 * 64];
  __shared__ u16 lsV[2][64 * 64];
  __shared__ u16 lsP[8][16 * 64];
  const int hw = blockIdx.x;
  const int xcd = hw & 7, vv = hw >> 3;
  const int by = xcd * 8 + (vv >> 3);  // (b*16+h), grouped per XCD for K/V L2 residency
  const int j = vv & 7;                // pair (j, 15-j) of 128-row q-tiles
  const int tid = threadIdx.x;
  const int w = tid >> 6, lane = tid & 63;
  const int c = lane & 15, qr = lane >> 4;
  const int b = by >> 4, h = by & 15;
  u16* lp = lsP[w];

  const int q0A = j * 128 + w * 16;
  const int q0B = (15 - j) * 128 + w * 16;
  const int ndA = q0A >> 6, ndB = q0B >> 6;
  const int ntiles = 32 - 2 * j;  // always even

  const u16* qra = Q + ((size_t)by * S_LEN + q0A + c) * DHEAD;
  const u16* qrb = Q + ((size_t)by * S_LEN + q0B + c) * DHEAD;
  const bf16x8 aQA0 = *(const bf16x8*)(qra + qr * 8);
  const bf16x8 aQA1 = *(const bf16x8*)(qra + 32 + qr * 8);
  const bf16x8 aQB0 = *(const bf16x8*)(qrb + qr * 8);
  const bf16x8 aQB1 = *(const bf16x8*)(qrb + 32 + qr * 8);

  f32x4 oA[4], oB[4];
#pragma unroll
  for (int d = 0; d < 4; ++d) { oA[d] = (f32x4){0.f, 0.f, 0.f, 0.f}; oB[d] = oA[d]; }
  float mA = -1e30f, lA_ = 0.f, mB = -1e30f, lB_ = 0.f;

  auto stage = [&](int kt, int bsel) {
    const int kv0 = kt * 64;
    int r = tid >> 3, p = tid & 7;
    int ps = p ^ (r & 7);
    gld_lds16(K + ((size_t)by * S_LEN + kv0 + r) * DHEAD + ps * 8, &lsK[bsel][(w * 64) * 8]);
    gld_lds16(Vt + ((size_t)by * DHEAD + r) * S_LEN + kv0 + ps * 8, &lsV[bsel][(w * 64) * 8]);
  };

  auto process = [&](const u16* bK, const u16* bV, int kt, int nd, int q0,
                     const bf16x8& aQ0, const bf16x8& aQ1,
                     f32x4* o_acc, float& m_run, float& l_run) {
    const int kv0 = kt * 64;
    f32x4 sc[4];
    __builtin_amdgcn_s_setprio(1);
#pragma unroll
    for (int nt = 0; nt < 4; ++nt) {
      int row = nt * 16 + c;
      const bf16x8 k0 = *(const bf16x8*)(bK + row * 64 + ((qr ^ (row & 7)) * 8));
      const bf16x8 k1 = *(const bf16x8*)(bK + row * 64 + (((4 + qr) ^ (row & 7)) * 8));
      f32x4 z = (f32x4){0.f, 0.f, 0.f, 0.f};
      z = __builtin_amdgcn_mfma_f32_16x16x32_bf16(k0, aQ0, z, 0, 0, 0);
      z = __builtin_amdgcn_mfma_f32_16x16x32_bf16(k1, aQ1, z, 0, 0, 0);
      sc[nt] = z;
    }
    __builtin_amdgcn_s_setprio(0);

    if (kt == nd) {
#pragma unroll
      for (int nt = 0; nt < 4; ++nt)
#pragma unroll
        for (int r = 0; r < 4; ++r) {
          int k_g = kv0 + nt * 16 + qr * 4 + r;
          int q_g = q0 + c;
          if (k_g > q_g) sc[nt][r] = -1e30f;
        }
    }

    float tm = fmaxf(fmaxf(fmaxf(sc[0][0], sc[0][1]), fmaxf(sc[0][2], sc[0][3])),
                     fmaxf(fmaxf(sc[1][0], sc[1][1]), fmaxf(sc[1][2], sc[1][3])));
    tm = fmaxf(tm, fmaxf(fmaxf(fmaxf(sc[2][0], sc[2][1]), fmaxf(sc[2][2], sc[2][3])),
                         fmaxf(fmaxf(sc[3][0], sc[3][1]), fmaxf(sc[3][2], sc[3][3]))));
    tm = fmaxf(tm, __shfl_xor(tm, 16));
    tm = fmaxf(tm, __shfl_xor(tm, 32));
    if (tm > m_run + 11.5f) {  // defer-max (log2 domain, ~e^8)
      float al = __builtin_amdgcn_exp2f(m_run - tm);
      l_run *= al;
#pragma unroll
      for (int dt = 0; dt < 4; ++dt)
#pragma unroll
        for (int r = 0; r < 4; ++r) o_acc[dt][r] *= al;
      m_run = tm;
    }
    float rs = 0.f;
#pragma unroll
    for (int nt = 0; nt < 4; ++nt) {
      float p0 = __builtin_amdgcn_exp2f(sc[nt][0] - m_run);
      float p1 = __builtin_amdgcn_exp2f(sc[nt][1] - m_run);
      float p2 = __builtin_amdgcn_exp2f(sc[nt][2] - m_run);
      float p3 = __builtin_amdgcn_exp2f(sc[nt][3] - m_run);
      rs += (p0 + p1) + (p2 + p3);
      // truncating bf16 pack: one v_perm per pair
      u32 w01 = __builtin_amdgcn_perm(__builtin_bit_cast(u32, p1), __builtin_bit_cast(u32, p0), 0x07060302u);
      u32 w23 = __builtin_amdgcn_perm(__builtin_bit_cast(u32, p3), __builtin_bit_cast(u32, p2), 0x07060302u);
      uint2 pk; pk.x = w01; pk.y = w23;
      *reinterpret_cast<uint2*>(lp + c * 64 + (((nt * 4 + qr) ^ c) * 4)) = pk;
    }
    rs += __shfl_xor(rs, 16);
    rs += __shfl_xor(rs, 32);
    l_run += rs;

    bf16x8 pb[2];
#pragma unroll
    for (int ks = 0; ks < 2; ++ks) {
      bf16x4 lo = *(const bf16x4*)(lp + c * 64 + (((ks * 8 + qr * 2) ^ c) * 4));
      bf16x4 hi = *(const bf16x4*)(lp + c * 64 + (((ks * 8 + qr * 2 + 1) ^ c) * 4));
      pb[ks] = (bf16x8){lo[0], lo[1], lo[2], lo[3], hi[0], hi[1], hi[2], hi[3]};
    }
    __builtin_amdgcn_s_setprio(1);
#pragma unroll
    for (int dt = 0; dt < 4; ++dt) {
      int rowv = dt * 16 + c;
#pragma unroll
      for (int ks = 0; ks < 2; ++ks) {
        const bf16x8 vb = *(const bf16x8*)(bV + rowv * 64 + (((ks * 4 + qr) ^ (rowv & 7)) * 8));
        o_acc[dt] = __builtin_amdgcn_mfma_f32_16x16x32_bf16(vb, pb[ks], o_acc[dt], 0, 0, 0);
      }
    }
    __builtin_amdgcn_s_setprio(0);
  };

  stage(0, 0);
  __syncthreads();
  for (int kt = 0; kt < ntiles; kt += 2) {
    if (kt + 1 < ntiles) stage(kt + 1, 1);
    if (kt <= ndB) process(lsK[0], lsV[0], kt, ndB, q0B, aQB0, aQB1, oB, mB, lB_);
    if (kt <= ndA) process(lsK[0], lsV[0], kt, ndA, q0A, aQA0, aQA1, oA, mA, lA_);
    __syncthreads();
    const int k2 = kt + 1;
    if (k2 + 1 < ntiles) stage(k2 + 1, 0);
    if (k2 <= ndB) process(lsK[1], lsV[1], k2, ndB, q0B, aQB0, aQB1, oB, mB, lB_);
    if (k2 <= ndA) process(lsK[1], lsV[1], k2, ndA, q0A, aQA0, aQA1, oA, mA, lA_);
    __syncthreads();
  }

  {
    float rl = 1.0f / lB_;
    int s = q0B + c;
#pragma unroll
    for (int dt = 0; dt < 4; ++dt) {
      ushort4 ok;
#pragma unroll
      for (int r = 0; r < 4; ++r) ((u16*)&ok)[r] = f2bf(oB[dt][r] * rl);
      *reinterpret_cast<ushort4*>(O + (((size_t)b * S_LEN + s) * NHEAD + h) * DHEAD + dt * 16 + qr * 4) = ok;
    }
  }
  {
    float rl = 1.0f / lA_;
    int s = q0A + c;
#pragma unroll
    for (int dt = 0; dt < 4; ++dt) {
      ushort4 ok;
#pragma unroll
      for (int r = 0; r < 4; ++r) ((u16*)&ok)[r] = f2bf(oA[dt][r] * rl);
      *reinterpret_cast<ushort4*>(O + (((size_t)b * S_LEN + s) * NHEAD + h) * DHEAD + dt * 16 + qr * 4) = ok;
    }
  }
}

extern "C" void kernel_launch(void* const* d_in, const int* in_sizes, int n_in,
                              void* d_out, int out_size, void* d_ws, size_t ws_size,
                              hipStream_t stream) {
  (void)in_sizes; (void)n_in; (void)out_size; (void)ws_size;
  const float* x  = (const float*)d_in[0];
  const float* Wq = (const float*)d_in[1];
  const float* Wk = (const float*)d_in[2];
  const float* Wv = (const float*)d_in[3];
  const float* Wo = (const float*)d_in[4];

  u16* ws  = (u16*)d_ws;
  u16* xb  = ws;                  // 8192*1024
  u16* wqb = xb  + 8388608;       // [Wq;Wk;Wv;Wo] contiguous
  u16* wob = wqb + 3145728;
  u16* Qb  = wqb + 4194304;       // [B][H][S][DH] (scaled by 0.125*log2e)
  u16* Kb  = Qb  + 8388608;       // [B][H][S][DH]
  u16* Vt  = Kb  + 8388608;       // [B*H][DH][S]
  u16* Ob  = Vt  + 8388608;       // [B][S][H][DH]

  cast_bf16_kernel<<<8192, 256, 0, stream>>>(x, xb, 2097152);
  cast_w_kernel<<<4096, 256, 0, stream>>>(Wq, Wk, Wv, Wo, wqb);

  gemm_qkv<<<384, 512, 0, stream>>>(xb, wqb, Qb);
  attn_kernel<<<512, 512, 0, stream>>>(Qb, Kb, Vt, Ob);
  gemm_bt<<<512, 256, 0, stream>>>(Ob, wob, (float*)d_out);
}

// Round 5
// 178.389 us; speedup vs baseline: 2.1820x; 1.0291x over previous
//
#include <hip/hip_runtime.h>

typedef unsigned short u16;
typedef unsigned int u32;
typedef __attribute__((ext_vector_type(8))) short bf16x8;
typedef __attribute__((ext_vector_type(4))) short bf16x4;
typedef __attribute__((ext_vector_type(4))) float f32x4;

#define S_LEN 2048
#define NHEAD 16
#define DHEAD 64
#define DMODEL 1024

__device__ __forceinline__ u16 f2bf(float f) {
  unsigned u = __builtin_bit_cast(unsigned, f);
  unsigned r = (u + 0x7fffu + ((u >> 16) & 1u)) >> 16;
  return (u16)r;
}

__device__ __forceinline__ void gld_lds16(const void* g, void* l) {
  __builtin_amdgcn_global_load_lds((const __attribute__((address_space(1))) unsigned*)g,
                                   (__attribute__((address_space(3))) unsigned*)l,
                                   16, 0, 0);
}

__global__ void cast_bf16_kernel(const float* __restrict__ in, u16* __restrict__ out, int n4) {
  int i = blockIdx.x * 256 + threadIdx.x;
  if (i >= n4) return;
  float4 v = reinterpret_cast<const float4*>(in)[i];
  ushort4 o;
  o.x = f2bf(v.x); o.y = f2bf(v.y); o.z = f2bf(v.z); o.w = f2bf(v.w);
  reinterpret_cast<ushort4*>(out)[i] = o;
}

__global__ void cast_w_kernel(const float* __restrict__ Wq, const float* __restrict__ Wk,
                              const float* __restrict__ Wv, const float* __restrict__ Wo,
                              u16* __restrict__ out) {
  int id = blockIdx.x * 256 + threadIdx.x;
  int wsel = id >> 18, j = id & 262143;
  const float* s = wsel < 2 ? (wsel == 0 ? Wq : Wk) : (wsel == 2 ? Wv : Wo);
  float4 v = reinterpret_cast<const float4*>(s)[j];
  ushort4 o;
  o.x = f2bf(v.x); o.y = f2bf(v.y); o.z = f2bf(v.z); o.w = f2bf(v.w);
  reinterpret_cast<ushort4*>(out)[id] = o;
}

// ------------------- fused QKV GEMM: 256x256 tile, BK=64, 8-phase schedule -------------------
// C = A(8192x1024) * B^T (B = [Wq;Wk;Wv] 3072x1024). 512 thr = 8 waves (2M x 4N), per-wave 128x64.
// LDS 128KiB: [buf2][A,B][half2][128][64] bf16. FULL 3-bit row swizzle: LDS[r][cb] holds global
// chunk cb^(r&7) (16B chunks) — inverse applied on global_load_lds source, matching XOR on
// ds_read (rule #21 both-sides). Bank math: row stride 128B = 0 mod 32 dwords, so only the
// in-row chunk spreads banks; chunk^(row&7) gives 2 lanes/chunk = conflict-free (m136).
// vmcnt(6) only at phases 4/8 (counted, never 0 mid-loop). Epilogue scatters Q(scaled)/K/V^T.
#define MFMA_Q(mlo, nlo)                                                                     \
  _Pragma("unroll") for (int m_ = 0; m_ < 4; ++m_)                                           \
  _Pragma("unroll") for (int n_ = 0; n_ < 2; ++n_)                                           \
  _Pragma("unroll") for (int kk_ = 0; kk_ < 2; ++kk_)                                        \
    acc[(mlo) + m_][(nlo) + n_] = __builtin_amdgcn_mfma_f32_16x16x32_bf16(                   \
        af[(mlo) + m_][kk_], bf[(nlo) + n_][kk_], acc[(mlo) + m_][(nlo) + n_], 0, 0, 0);

#define VM6 do { __builtin_amdgcn_sched_barrier(0);                                          \
  asm volatile("s_waitcnt vmcnt(6)" ::: "memory");                                           \
  __builtin_amdgcn_sched_barrier(0); } while (0)
#define VM0 do { __builtin_amdgcn_sched_barrier(0);                                          \
  asm volatile("s_waitcnt vmcnt(0)" ::: "memory");                                           \
  __builtin_amdgcn_sched_barrier(0); } while (0)

#define HALF_ITER(bb, S1, S2, S3, S4, WAIT) do {                                             \
  const u16* aB = aB0 + (bb)*32768;                                                          \
  const u16* bB = bB0 + (bb)*32768;                                                          \
  /* P1 */                                                                                   \
  _Pragma("unroll") for (int m_ = 0; m_ < 4; ++m_) {                                         \
    af[m_][0] = rdA(aB, m_, 0); af[m_][1] = rdA(aB, m_, 1); }                                \
  _Pragma("unroll") for (int n_ = 0; n_ < 2; ++n_) {                                         \
    bf[n_][0] = rdB(bB, n_, 0); bf[n_][1] = rdB(bB, n_, 1); }                                \
  S1;                                                                                        \
  __builtin_amdgcn_s_barrier();                                                              \
  __builtin_amdgcn_s_setprio(1); MFMA_Q(0, 0) __builtin_amdgcn_s_setprio(0);                 \
  __builtin_amdgcn_s_barrier();                                                              \
  /* P2 */                                                                                   \
  _Pragma("unroll") for (int m_ = 0; m_ < 4; ++m_) {                                         \
    af[4 + m_][0] = rdA(aB, 4 + m_, 0); af[4 + m_][1] = rdA(aB, 4 + m_, 1); }                \
  S2;                                                                                        \
  __builtin_amdgcn_s_barrier();                                                              \
  __builtin_amdgcn_s_setprio(1); MFMA_Q(4, 0) __builtin_amdgcn_s_setprio(0);                 \
  __builtin_amdgcn_s_barrier();                                                              \
  /* P3 */                                                                                   \
  _Pragma("unroll") for (int n_ = 0; n_ < 2; ++n_) {                                         \
    bf[2 + n_][0] = rdB(bB, 2 + n_, 0); bf[2 + n_][1] = rdB(bB, 2 + n_, 1); }                \
  S3;                                                                                        \
  __builtin_amdgcn_s_barrier();                                                              \
  __builtin_amdgcn_s_setprio(1); MFMA_Q(0, 2) __builtin_amdgcn_s_setprio(0);                 \
  __builtin_amdgcn_s_barrier();                                                              \
  /* P4 */                                                                                   \
  S4;                                                                                        \
  __builtin_amdgcn_s_barrier();                                                              \
  __builtin_amdgcn_s_setprio(1); MFMA_Q(4, 2) __builtin_amdgcn_s_setprio(0);                 \
  WAIT;                                                                                      \
  __builtin_amdgcn_s_barrier();                                                              \
} while (0)

__global__ __launch_bounds__(512, 2) void gemm_qkv(const u16* __restrict__ A,
                                                   const u16* __restrict__ Bw,
                                                   u16* __restrict__ Qb) {
  __shared__ u16 lds[65536];  // 128 KiB
  const int bid = blockIdx.x;
  const int xcd = bid & 7, v = bid >> 3;           // 48 blocks / XCD (384 % 8 == 0, bijective)
  const int by = xcd * 4 + (v & 3), bx = v >> 2;   // by 0..31 (M), bx 0..11 (N)
  const int brow = by * 256, bcol = bx * 256;
  const int tid = threadIdx.x;
  const int w = tid >> 6, lane = tid & 63;
  const int wm = w >> 2, wn = w & 3;
  const int c = lane & 15, qr = lane >> 4;
  const int sqz = (qr ^ (c & 7)) * 8;  // swizzled chunk offset (u16 units), kk=1 adds ^32

  auto stg = [&](int mat, int tau, int half) {
    if (tau >= 16) return;
    u16* region = lds + (tau & 1) * 32768 + mat * 16384 + half * 8192;
    const u16* G = mat ? Bw : A;
    int rowb = (mat ? bcol : brow) + half * 128;
    int k0 = tau * 64;
#pragma unroll
    for (int i = 0; i < 2; ++i) {
      int slot = i * 512 + tid;
      int r = slot >> 3, cb = slot & 7;
      int cbs = cb ^ (r & 7);  // inverse 3-bit swizzle on global source
      gld_lds16(G + (size_t)(rowb + r) * DMODEL + k0 + cbs * 8, region + (i * 512 + w * 64) * 8);
    }
  };

  auto rdA = [&](const u16* base, int m, int kk) {
    return *(const bf16x8*)(base + (m * 16 + c) * 64 + (sqz ^ (kk << 5)));
  };
  auto rdB = [&](const u16* base, int n, int kk) {
    return *(const bf16x8*)(base + ((wn & 1) * 64 + n * 16 + c) * 64 + (sqz ^ (kk << 5)));
  };

  f32x4 acc[8][4];
#pragma unroll
  for (int m = 0; m < 8; ++m)
#pragma unroll
    for (int n = 0; n < 4; ++n) acc[m][n] = (f32x4){0.f, 0.f, 0.f, 0.f};
  bf16x8 af[8][2], bf[4][2];
  const u16* aB0 = lds + wm * 8192;
  const u16* bB0 = lds + 16384 + (wn >> 1) * 8192;

  // prologue: T0 complete + T1 {A0,A1,B0}; vmcnt(6) drains the 8 oldest (= all of T0)
  stg(0, 0, 0); stg(0, 0, 1); stg(1, 0, 0); stg(1, 0, 1);
  stg(0, 1, 0); stg(0, 1, 1); stg(1, 1, 0);
  VM6;
  __builtin_amdgcn_s_barrier();

#pragma unroll 1
  for (int t = 0; t < 8; ++t) {
    const int e = 2 * t;
    // phases 1-4: K-tile e (buf0); stage (e+1).B1, (e+2).{A0,A1,B0}
    HALF_ITER(0,
              stg(1, e + 1, 1),
              stg(0, e + 2, 0),
              stg(0, e + 2, 1),
              stg(1, e + 2, 0),
              if (t < 7) { VM6; } else { VM0; });
    // phases 5-8: K-tile e+1 (buf1); stage (e+2).B1, (e+3).{A0,A1,B0}
    HALF_ITER(1,
              stg(1, e + 2, 1),
              stg(0, e + 3, 0),
              stg(0, e + 3, 1),
              stg(1, e + 3, 0),
              if (t < 7) { VM6; });
  }

  // epilogue: scatter Q (scaled, exp2-domain), K, V^T
  u16* Kb = Qb + 8388608;
  u16* Vt = Kb + 8388608;
#pragma unroll
  for (int m = 0; m < 8; ++m) {
#pragma unroll
    for (int n = 0; n < 4; ++n) {
      f32x4 a = acc[m][n];
      int gm0 = brow + wm * 128 + m * 16 + qr * 4;
      int gn = bcol + wn * 64 + n * 16 + c;
      int mat = gn >> 10, gl = gn & 1023;
      int hh = gl >> 6, dh = gl & 63;
      int b = gm0 >> 11;
      if (mat == 2) {  // V transposed: [B*H][DH][S], 4 consecutive s
        int s0 = gm0 & 2047;
        ushort4 pk;
        pk.x = f2bf(a[0]); pk.y = f2bf(a[1]); pk.z = f2bf(a[2]); pk.w = f2bf(a[3]);
        *reinterpret_cast<ushort4*>(Vt + ((size_t)(b * NHEAD + hh) * DHEAD + dh) * S_LEN + s0) = pk;
      } else {
        float scale = (mat == 0) ? 0.1803368801111204f : 1.0f;  // 0.125 * log2(e) for Q
        u16* dst = (mat == 0) ? Qb : Kb;
#pragma unroll
        for (int r = 0; r < 4; ++r) {
          int gm = gm0 + r;
          int s = gm & 2047;
          dst[((size_t)(b * NHEAD + hh) * S_LEN + s) * DHEAD + dh] = f2bf(a[r] * scale);
        }
      }
    }
  }
}

// ------------------- AO projection: 128x128 tile, BK=32, 2-phase dbuf -------------------
__global__ __launch_bounds__(256) void gemm_bt(const u16* __restrict__ A, const u16* __restrict__ Bw,
                                               float* __restrict__ outp) {
  __shared__ u16 lA[2][128 * 32];
  __shared__ u16 lB[2][128 * 32];
  const int hw = blockIdx.x;
  const int xcd = hw & 7, vv = hw >> 3;
  const int bx = vv >> 3, by = xcd * 8 + (vv & 7);
  const int tid = threadIdx.x;
  const int w = tid >> 6, lane = tid & 63;
  const int wm = w >> 1, wn = w & 1;
  const int c = lane & 15, qr = lane >> 4;
  const int brow = by * 128, bcol = bx * 128;
  f32x4 acc[4][4];
#pragma unroll
  for (int m = 0; m < 4; ++m)
#pragma unroll
    for (int n = 0; n < 4; ++n) acc[m][n] = (f32x4){0.f, 0.f, 0.f, 0.f};

  auto stage = [&](int kt, int bsel) {
    const int k0 = kt * 32;
#pragma unroll
    for (int i = 0; i < 2; ++i) {
      int slot = i * 256 + w * 64 + lane;
      int r = slot >> 2, sg = slot & 3;
      gld_lds16(A + (size_t)(brow + r) * DMODEL + k0 + sg * 8, &lA[bsel][(i * 256 + w * 64) * 8]);
      gld_lds16(Bw + (size_t)(bcol + r) * DMODEL + k0 + sg * 8, &lB[bsel][(i * 256 + w * 64) * 8]);
    }
  };

  stage(0, 0);
  __syncthreads();
  int cur = 0;
  for (int kt = 0; kt < 32; ++kt) {
    if (kt < 31) stage(kt + 1, cur ^ 1);
    bf16x8 af[4], bfr[4];
#pragma unroll
    for (int m = 0; m < 4; ++m) af[m] = *(const bf16x8*)(&lA[cur][(wm * 64 + m * 16 + c) * 32 + qr * 8]);
#pragma unroll
    for (int n = 0; n < 4; ++n) bfr[n] = *(const bf16x8*)(&lB[cur][(wn * 64 + n * 16 + c) * 32 + qr * 8]);
    __builtin_amdgcn_s_setprio(1);
#pragma unroll
    for (int m = 0; m < 4; ++m)
#pragma unroll
      for (int n = 0; n < 4; ++n)
        acc[m][n] = __builtin_amdgcn_mfma_f32_16x16x32_bf16(af[m], bfr[n], acc[m][n], 0, 0, 0);
    __builtin_amdgcn_s_setprio(0);
    __syncthreads();
    cur ^= 1;
  }

  const int rb = qr * 4;
#pragma unroll
  for (int m = 0; m < 4; ++m)
#pragma unroll
    for (int n = 0; n < 4; ++n) {
      f32x4 a = acc[m][n];
      int gm0 = brow + wm * 64 + m * 16 + rb;
      int gn = bcol + wn * 64 + n * 16 + c;
#pragma unroll
      for (int r = 0; r < 4; ++r) outp[(size_t)(gm0 + r) * DMODEL + gn] = a[r];
    }
}

// ------------------- causal flash attention (swapped operands, exp2 domain) -------------------
__global__ __launch_bounds__(512, 4) void attn_kernel(const u16* __restrict__ Q, const u16* __restrict__ K,
                                                      const u16* __restrict__ Vt, u16* __restrict__ O) {
  __shared__ u16 lsK[2][64 * 64];
  __shared__ u16 lsV[2][64 * 64];
  __shared__ u16 lsP[8][16 * 64];
  const int hw = blockIdx.x;
  const int xcd = hw & 7, vv = hw >> 3;
  const int by = xcd * 8 + (vv >> 3);  // (b*16+h), grouped per XCD for K/V L2 residency
  const int j = vv & 7;                // pair (j, 15-j) of 128-row q-tiles
  const int tid = threadIdx.x;
  const int w = tid >> 6, lane = tid & 63;
  const int c = lane & 15, qr = lane >> 4;
  const int b = by >> 4, h = by & 15;
  u16* lp = lsP[w];

  const int q0A = j * 128 + w * 16;
  const int q0B = (15 - j) * 128 + w * 16;
  const int ndA = q0A >> 6, ndB = q0B >> 6;
  const int ntiles = 32 - 2 * j;  // always even

  const u16* qra = Q + ((size_t)by * S_LEN + q0A + c) * DHEAD;
  const u16* qrb = Q + ((size_t)by * S_LEN + q0B + c) * DHEAD;
  const bf16x8 aQA0 = *(const bf16x8*)(qra + qr * 8);
  const bf16x8 aQA1 = *(const bf16x8*)(qra + 32 + qr * 8);
  const bf16x8 aQB0 = *(const bf16x8*)(qrb + qr * 8);
  const bf16x8 aQB1 = *(const bf16x8*)(qrb + 32 + qr * 8);

  f32x4 oA[4], oB[4];
#pragma unroll
  for (int d = 0; d < 4; ++d) { oA[d] = (f32x4){0.f, 0.f, 0.f, 0.f}; oB[d] = oA[d]; }
  float mA = -1e30f, lA_ = 0.f, mB = -1e30f, lB_ = 0.f;

  auto stage = [&](int kt, int bsel) {
    const int kv0 = kt * 64;
    int r = tid >> 3, p = tid & 7;
    int ps = p ^ (r & 7);
    gld_lds16(K + ((size_t)by * S_LEN + kv0 + r) * DHEAD + ps * 8, &lsK[bsel][(w * 64) * 8]);
    gld_lds16(Vt + ((size_t)by * DHEAD + r) * S_LEN + kv0 + ps * 8, &lsV[bsel][(w * 64) * 8]);
  };

  auto process = [&](const u16* bK, const u16* bV, int kt, int nd, int q0,
                     const bf16x8& aQ0, const bf16x8& aQ1,
                     f32x4* o_acc, float& m_run, float& l_run) {
    const int kv0 = kt * 64;
    f32x4 sc[4];
    __builtin_amdgcn_s_setprio(1);
#pragma unroll
    for (int nt = 0; nt < 4; ++nt) {
      int row = nt * 16 + c;
      const bf16x8 k0 = *(const bf16x8*)(bK + row * 64 + ((qr ^ (row & 7)) * 8));
      const bf16x8 k1 = *(const bf16x8*)(bK + row * 64 + (((4 + qr) ^ (row & 7)) * 8));
      f32x4 z = (f32x4){0.f, 0.f, 0.f, 0.f};
      z = __builtin_amdgcn_mfma_f32_16x16x32_bf16(k0, aQ0, z, 0, 0, 0);
      z = __builtin_amdgcn_mfma_f32_16x16x32_bf16(k1, aQ1, z, 0, 0, 0);
      sc[nt] = z;
    }
    __builtin_amdgcn_s_setprio(0);

    if (kt == nd) {
#pragma unroll
      for (int nt = 0; nt < 4; ++nt)
#pragma unroll
        for (int r = 0; r < 4; ++r) {
          int k_g = kv0 + nt * 16 + qr * 4 + r;
          int q_g = q0 + c;
          if (k_g > q_g) sc[nt][r] = -1e30f;
        }
    }

    float tm = fmaxf(fmaxf(fmaxf(sc[0][0], sc[0][1]), fmaxf(sc[0][2], sc[0][3])),
                     fmaxf(fmaxf(sc[1][0], sc[1][1]), fmaxf(sc[1][2], sc[1][3])));
    tm = fmaxf(tm, fmaxf(fmaxf(fmaxf(sc[2][0], sc[2][1]), fmaxf(sc[2][2], sc[2][3])),
                         fmaxf(fmaxf(sc[3][0], sc[3][1]), fmaxf(sc[3][2], sc[3][3]))));
    tm = fmaxf(tm, __shfl_xor(tm, 16));
    tm = fmaxf(tm, __shfl_xor(tm, 32));
    if (tm > m_run + 11.5f) {  // defer-max (log2 domain, ~e^8)
      float al = __builtin_amdgcn_exp2f(m_run - tm);
      l_run *= al;
#pragma unroll
      for (int dt = 0; dt < 4; ++dt)
#pragma unroll
        for (int r = 0; r < 4; ++r) o_acc[dt][r] *= al;
      m_run = tm;
    }
    float rs = 0.f;
#pragma unroll
    for (int nt = 0; nt < 4; ++nt) {
      float p0 = __builtin_amdgcn_exp2f(sc[nt][0] - m_run);
      float p1 = __builtin_amdgcn_exp2f(sc[nt][1] - m_run);
      float p2 = __builtin_amdgcn_exp2f(sc[nt][2] - m_run);
      float p3 = __builtin_amdgcn_exp2f(sc[nt][3] - m_run);
      rs += (p0 + p1) + (p2 + p3);
      u32 w01 = __builtin_amdgcn_perm(__builtin_bit_cast(u32, p1), __builtin_bit_cast(u32, p0), 0x07060302u);
      u32 w23 = __builtin_amdgcn_perm(__builtin_bit_cast(u32, p3), __builtin_bit_cast(u32, p2), 0x07060302u);
      uint2 pk; pk.x = w01; pk.y = w23;
      *reinterpret_cast<uint2*>(lp + c * 64 + (((nt * 4 + qr) ^ c) * 4)) = pk;
    }
    rs += __shfl_xor(rs, 16);
    rs += __shfl_xor(rs, 32);
    l_run += rs;

    bf16x8 pb[2];
#pragma unroll
    for (int ks = 0; ks < 2; ++ks) {
      bf16x4 lo = *(const bf16x4*)(lp + c * 64 + (((ks * 8 + qr * 2) ^ c) * 4));
      bf16x4 hi = *(const bf16x4*)(lp + c * 64 + (((ks * 8 + qr * 2 + 1) ^ c) * 4));
      pb[ks] = (bf16x8){lo[0], lo[1], lo[2], lo[3], hi[0], hi[1], hi[2], hi[3]};
    }
    __builtin_amdgcn_s_setprio(1);
#pragma unroll
    for (int dt = 0; dt < 4; ++dt) {
      int rowv = dt * 16 + c;
#pragma unroll
      for (int ks = 0; ks < 2; ++ks) {
        const bf16x8 vb = *(const bf16x8*)(bV + rowv * 64 + (((ks * 4 + qr) ^ (rowv & 7)) * 8));
        o_acc[dt] = __builtin_amdgcn_mfma_f32_16x16x32_bf16(vb, pb[ks], o_acc[dt], 0, 0, 0);
      }
    }
    __builtin_amdgcn_s_setprio(0);
  };

  stage(0, 0);
  __syncthreads();
  for (int kt = 0; kt < ntiles; kt += 2) {
    if (kt + 1 < ntiles) stage(kt + 1, 1);
    if (kt <= ndB) process(lsK[0], lsV[0], kt, ndB, q0B, aQB0, aQB1, oB, mB, lB_);
    if (kt <= ndA) process(lsK[0], lsV[0], kt, ndA, q0A, aQA0, aQA1, oA, mA, lA_);
    __syncthreads();
    const int k2 = kt + 1;
    if (k2 + 1 < ntiles) stage(k2 + 1, 0);
    if (k2 <= ndB) process(lsK[1], lsV[1], k2, ndB, q0B, aQB0, aQB1, oB, mB, lB_);
    if (k2 <= ndA) process(lsK[1], lsV[1], k2, ndA, q0A, aQA0, aQA1, oA, mA, lA_);
    __syncthreads();
  }

  {
    float rl = 1.0f / lB_;
    int s = q0B + c;
#pragma unroll
    for (int dt = 0; dt < 4; ++dt) {
      ushort4 ok;
#pragma unroll
      for (int r = 0; r < 4; ++r) ((u16*)&ok)[r] = f2bf(oB[dt][r] * rl);
      *reinterpret_cast<ushort4*>(O + (((size_t)b * S_LEN + s) * NHEAD + h) * DHEAD + dt * 16 + qr * 4) = ok;
    }
  }
  {
    float rl = 1.0f / lA_;
    int s = q0A + c;
#pragma unroll
    for (int dt = 0; dt < 4; ++dt) {
      ushort4 ok;
#pragma unroll
      for (int r = 0; r < 4; ++r) ((u16*)&ok)[r] = f2bf(oA[dt][r] * rl);
      *reinterpret_cast<ushort4*>(O + (((size_t)b * S_LEN + s) * NHEAD + h) * DHEAD + dt * 16 + qr * 4) = ok;
    }
  }
}

extern "C" void kernel_launch(void* const* d_in, const int* in_sizes, int n_in,
                              void* d_out, int out_size, void* d_ws, size_t ws_size,
                              hipStream_t stream) {
  (void)in_sizes; (void)n_in; (void)out_size; (void)ws_size;
  const float* x  = (const float*)d_in[0];
  const float* Wq = (const float*)d_in[1];
  const float* Wk = (const float*)d_in[2];
  const float* Wv = (const float*)d_in[3];
  const float* Wo = (const float*)d_in[4];

  u16* ws  = (u16*)d_ws;
  u16* xb  = ws;                  // 8192*1024
  u16* wqb = xb  + 8388608;       // [Wq;Wk;Wv;Wo] contiguous
  u16* wob = wqb + 3145728;
  u16* Qb  = wqb + 4194304;       // [B][H][S][DH] (scaled by 0.125*log2e)
  u16* Kb  = Qb  + 8388608;       // [B][H][S][DH]
  u16* Vt  = Kb  + 8388608;       // [B*H][DH][S]
  u16* Ob  = Vt  + 8388608;       // [B][S][H][DH]

  cast_bf16_kernel<<<8192, 256, 0, stream>>>(x, xb, 2097152);
  cast_w_kernel<<<4096, 256, 0, stream>>>(Wq, Wk, Wv, Wo, wqb);

  gemm_qkv<<<384, 512, 0, stream>>>(xb, wqb, Qb);
  attn_kernel<<<512, 512, 0, stream>>>(Qb, Kb, Vt, Ob);
  gemm_bt<<<512, 256, 0, stream>>>(Ob, wob, (float*)d_out);
}

// Round 6
// 173.838 us; speedup vs baseline: 2.2392x; 1.0262x over previous
//
#include <hip/hip_runtime.h>

typedef unsigned short u16;
typedef unsigned int u32;
typedef __attribute__((ext_vector_type(8))) short bf16x8;
typedef __attribute__((ext_vector_type(4))) short bf16x4;
typedef __attribute__((ext_vector_type(4))) float f32x4;

#define S_LEN 2048
#define NHEAD 16
#define DHEAD 64
#define DMODEL 1024

__device__ __forceinline__ u16 f2bf(float f) {
  unsigned u = __builtin_bit_cast(unsigned, f);
  unsigned r = (u + 0x7fffu + ((u >> 16) & 1u)) >> 16;
  return (u16)r;
}

__device__ __forceinline__ void gld_lds16(const void* g, void* l) {
  __builtin_amdgcn_global_load_lds((const __attribute__((address_space(1))) unsigned*)g,
                                   (__attribute__((address_space(3))) unsigned*)l,
                                   16, 0, 0);
}

__global__ void cast_bf16_kernel(const float* __restrict__ in, u16* __restrict__ out, int n4) {
  int i = blockIdx.x * 256 + threadIdx.x;
  if (i >= n4) return;
  float4 v = reinterpret_cast<const float4*>(in)[i];
  ushort4 o;
  o.x = f2bf(v.x); o.y = f2bf(v.y); o.z = f2bf(v.z); o.w = f2bf(v.w);
  reinterpret_cast<ushort4*>(out)[i] = o;
}

__global__ void cast_w_kernel(const float* __restrict__ Wq, const float* __restrict__ Wk,
                              const float* __restrict__ Wv, const float* __restrict__ Wo,
                              u16* __restrict__ out) {
  int id = blockIdx.x * 256 + threadIdx.x;
  int wsel = id >> 18, j = id & 262143;
  const float* s = wsel < 2 ? (wsel == 0 ? Wq : Wk) : (wsel == 2 ? Wv : Wo);
  float4 v = reinterpret_cast<const float4*>(s)[j];
  ushort4 o;
  o.x = f2bf(v.x); o.y = f2bf(v.y); o.z = f2bf(v.z); o.w = f2bf(v.w);
  reinterpret_cast<ushort4*>(out)[id] = o;
}

// ------------------- fused QKV GEMM: 256x192 tile, BK=64, 8-phase schedule -------------------
// C = A(8192x1024) * B^T (B = [Wq;Wk;Wv] 3072x1024). Grid 32x16 = 512 blocks = EXACTLY 2 full
// rounds at 1 block/CU (fixes the 384-block 75% pack). 512 thr = 8 waves (4M x 2N), per-wave
// 64x96 (acc[4][6]). LDS 112 KiB: per buf {A 256x64 | B 192x64}, 3-bit row swizzle both-sides
// (R5-verified conflict-free). Stage units: A-halves (2 loads/thr) + B-thirds (1 load/thr) =
// 7 loads/thr/K-tile; steady in-flight 12 -> vmcnt(5) at WAIT completes exactly tile e+1.
// Stage slots placed read-safe: B1,B2(e+1)@P1 (idle buf), A0,A1(e+2)@P3 (A reads done at P2),
// B0(e+2)@P4 (B reads done at P3).
#define MFMA_Q(mlo, nlo)                                                                     \
  _Pragma("unroll") for (int m_ = 0; m_ < 2; ++m_)                                           \
  _Pragma("unroll") for (int n_ = 0; n_ < 3; ++n_)                                           \
  _Pragma("unroll") for (int kk_ = 0; kk_ < 2; ++kk_)                                        \
    acc[(mlo) + m_][(nlo) + n_] = __builtin_amdgcn_mfma_f32_16x16x32_bf16(                   \
        af[(mlo) + m_][kk_], bf[(nlo) + n_][kk_], acc[(mlo) + m_][(nlo) + n_], 0, 0, 0);

#define VM5 do { __builtin_amdgcn_sched_barrier(0);                                          \
  asm volatile("s_waitcnt vmcnt(5)" ::: "memory");                                           \
  __builtin_amdgcn_sched_barrier(0); } while (0)
#define VM0 do { __builtin_amdgcn_sched_barrier(0);                                          \
  asm volatile("s_waitcnt vmcnt(0)" ::: "memory");                                           \
  __builtin_amdgcn_sched_barrier(0); } while (0)

#define HALF_ITER(bb, e, WAIT) do {                                                          \
  const u16* aW = aW0 + (bb)*28672;                                                          \
  const u16* bW = bW0 + (bb)*28672;                                                          \
  /* P1: read af m0-1, bf n0-2; stage B1,B2(e+1) into idle buf */                            \
  _Pragma("unroll") for (int m_ = 0; m_ < 2; ++m_) {                                         \
    af[m_][0] = rdA(aW, m_, 0); af[m_][1] = rdA(aW, m_, 1); }                                \
  _Pragma("unroll") for (int n_ = 0; n_ < 3; ++n_) {                                         \
    bf[n_][0] = rdB(bW, n_, 0); bf[n_][1] = rdB(bW, n_, 1); }                                \
  stgB((e) + 1, 1); stgB((e) + 1, 2);                                                        \
  __builtin_amdgcn_s_barrier();                                                              \
  __builtin_amdgcn_s_setprio(1); MFMA_Q(0, 0) __builtin_amdgcn_s_setprio(0);                 \
  __builtin_amdgcn_s_barrier();                                                              \
  /* P2: read af m2-3 */                                                                     \
  _Pragma("unroll") for (int m_ = 0; m_ < 2; ++m_) {                                         \
    af[2 + m_][0] = rdA(aW, 2 + m_, 0); af[2 + m_][1] = rdA(aW, 2 + m_, 1); }                \
  __builtin_amdgcn_s_barrier();                                                              \
  __builtin_amdgcn_s_setprio(1); MFMA_Q(2, 0) __builtin_amdgcn_s_setprio(0);                 \
  __builtin_amdgcn_s_barrier();                                                              \
  /* P3: read bf n3-5; stage A0,A1(e+2) (A region fully read at P2) */                       \
  _Pragma("unroll") for (int n_ = 0; n_ < 3; ++n_) {                                         \
    bf[3 + n_][0] = rdB(bW, 3 + n_, 0); bf[3 + n_][1] = rdB(bW, 3 + n_, 1); }                \
  stgA((e) + 2, 0); stgA((e) + 2, 1);                                                        \
  __builtin_amdgcn_s_barrier();                                                              \
  __builtin_amdgcn_s_setprio(1); MFMA_Q(0, 3) __builtin_amdgcn_s_setprio(0);                 \
  __builtin_amdgcn_s_barrier();                                                              \
  /* P4: stage B0(e+2) (B region fully read at P3) */                                        \
  stgB((e) + 2, 0);                                                                          \
  __builtin_amdgcn_s_barrier();                                                              \
  __builtin_amdgcn_s_setprio(1); MFMA_Q(2, 3) __builtin_amdgcn_s_setprio(0);                 \
  WAIT;                                                                                      \
  __builtin_amdgcn_s_barrier();                                                              \
} while (0)

__global__ __launch_bounds__(512, 2) void gemm_qkv(const u16* __restrict__ A,
                                                   const u16* __restrict__ Bw,
                                                   u16* __restrict__ Qb) {
  __shared__ u16 lds[57344];  // 112 KiB: [2buf][A 256x64 | B 192x64]
  const int bid = blockIdx.x;
  const int xcd = bid & 7, v = bid >> 3;           // 64 blocks/XCD (512 % 8 == 0, bijective)
  const int by = xcd * 4 + (v & 3), bx = v >> 2;   // by 0..31 (M), bx 0..15 (N)
  const int brow = by * 256, bcol = bx * 192;
  const int tid = threadIdx.x;
  const int w = tid >> 6, lane = tid & 63;
  const int wm = w >> 1, wn = w & 1;               // 4M x 2N waves
  const int c = lane & 15, qr = lane >> 4;
  const int sqz = (qr ^ (c & 7)) * 8;              // swizzled chunk offset (u16), kk=1 XORs 32

  auto stgA = [&](int tau, int half) {  // 128 rows, 2 loads/thread
    if (tau >= 16) return;
    u16* region = lds + (tau & 1) * 28672 + half * 8192;
    int rowb = brow + half * 128;
    int k0 = tau * 64;
#pragma unroll
    for (int i = 0; i < 2; ++i) {
      int slot = i * 512 + tid;
      int r = slot >> 3, cb = slot & 7;
      int cbs = cb ^ (r & 7);  // inverse 3-bit swizzle on global source
      gld_lds16(A + (size_t)(rowb + r) * DMODEL + k0 + cbs * 8, region + (i * 512 + w * 64) * 8);
    }
  };
  auto stgB = [&](int tau, int third) {  // 64 rows, 1 load/thread
    if (tau >= 16) return;
    u16* region = lds + (tau & 1) * 28672 + 16384 + third * 4096;
    int rowb = bcol + third * 64;
    int k0 = tau * 64;
    int r = tid >> 3, cb = tid & 7;
    int cbs = cb ^ (r & 7);
    gld_lds16(Bw + (size_t)(rowb + r) * DMODEL + k0 + cbs * 8, region + (w * 64) * 8);
  };

  auto rdA = [&](const u16* base, int m, int kk) {
    return *(const bf16x8*)(base + (m * 16 + c) * 64 + (sqz ^ (kk << 5)));
  };
  auto rdB = [&](const u16* base, int n, int kk) {
    return *(const bf16x8*)(base + (n * 16 + c) * 64 + (sqz ^ (kk << 5)));
  };

  f32x4 acc[4][6];
#pragma unroll
  for (int m = 0; m < 4; ++m)
#pragma unroll
    for (int n = 0; n < 6; ++n) acc[m][n] = (f32x4){0.f, 0.f, 0.f, 0.f};
  bf16x8 af[4][2], bf[6][2];
  const u16* aW0 = lds + wm * 4096;            // wave's 64-row A quarter
  const u16* bW0 = lds + 16384 + wn * 6144;    // wave's 96-row B half

  // prologue: tile0 full (7 loads) + tile1 {A0,A1,B0} (5); vmcnt(5) completes tile0
  stgA(0, 0); stgA(0, 1); stgB(0, 0); stgB(0, 1); stgB(0, 2);
  stgA(1, 0); stgA(1, 1); stgB(1, 0);
  VM5;
  __builtin_amdgcn_s_barrier();

#pragma unroll 1
  for (int t = 0; t < 8; ++t) {
    const int e = 2 * t;
    HALF_ITER(0, e, if (t < 7) { VM5; } else { VM0; });
    HALF_ITER(1, e + 1, if (t < 7) { VM5; });
  }

  // epilogue: scatter Q (scaled, exp2-domain), K, V^T
  u16* Kb = Qb + 8388608;
  u16* Vt = Kb + 8388608;
#pragma unroll
  for (int m = 0; m < 4; ++m) {
#pragma unroll
    for (int n = 0; n < 6; ++n) {
      f32x4 a = acc[m][n];
      int gm0 = brow + wm * 64 + m * 16 + qr * 4;
      int gn = bcol + wn * 96 + n * 16 + c;
      int mat = gn >> 10, gl = gn & 1023;
      int hh = gl >> 6, dh = gl & 63;
      int b = gm0 >> 11;
      if (mat == 2) {  // V transposed: [B*H][DH][S], 4 consecutive s
        int s0 = gm0 & 2047;
        ushort4 pk;
        pk.x = f2bf(a[0]); pk.y = f2bf(a[1]); pk.z = f2bf(a[2]); pk.w = f2bf(a[3]);
        *reinterpret_cast<ushort4*>(Vt + ((size_t)(b * NHEAD + hh) * DHEAD + dh) * S_LEN + s0) = pk;
      } else {
        float scale = (mat == 0) ? 0.1803368801111204f : 1.0f;  // 0.125 * log2(e) for Q
        u16* dst = (mat == 0) ? Qb : Kb;
#pragma unroll
        for (int r = 0; r < 4; ++r) {
          int gm = gm0 + r;
          int s = gm & 2047;
          dst[((size_t)(b * NHEAD + hh) * S_LEN + s) * DHEAD + dh] = f2bf(a[r] * scale);
        }
      }
    }
  }
}

// ------------------- AO projection: 128x128 tile, BK=32, 2-phase dbuf -------------------
__global__ __launch_bounds__(256) void gemm_bt(const u16* __restrict__ A, const u16* __restrict__ Bw,
                                               float* __restrict__ outp) {
  __shared__ u16 lA[2][128 * 32];
  __shared__ u16 lB[2][128 * 32];
  const int hw = blockIdx.x;
  const int xcd = hw & 7, vv = hw >> 3;
  const int bx = vv >> 3, by = xcd * 8 + (vv & 7);
  const int tid = threadIdx.x;
  const int w = tid >> 6, lane = tid & 63;
  const int wm = w >> 1, wn = w & 1;
  const int c = lane & 15, qr = lane >> 4;
  const int brow = by * 128, bcol = bx * 128;
  f32x4 acc[4][4];
#pragma unroll
  for (int m = 0; m < 4; ++m)
#pragma unroll
    for (int n = 0; n < 4; ++n) acc[m][n] = (f32x4){0.f, 0.f, 0.f, 0.f};

  auto stage = [&](int kt, int bsel) {
    const int k0 = kt * 32;
#pragma unroll
    for (int i = 0; i < 2; ++i) {
      int slot = i * 256 + w * 64 + lane;
      int r = slot >> 2, sg = slot & 3;
      gld_lds16(A + (size_t)(brow + r) * DMODEL + k0 + sg * 8, &lA[bsel][(i * 256 + w * 64) * 8]);
      gld_lds16(Bw + (size_t)(bcol + r) * DMODEL + k0 + sg * 8, &lB[bsel][(i * 256 + w * 64) * 8]);
    }
  };

  stage(0, 0);
  __syncthreads();
  int cur = 0;
  for (int kt = 0; kt < 32; ++kt) {
    if (kt < 31) stage(kt + 1, cur ^ 1);
    bf16x8 af[4], bfr[4];
#pragma unroll
    for (int m = 0; m < 4; ++m) af[m] = *(const bf16x8*)(&lA[cur][(wm * 64 + m * 16 + c) * 32 + qr * 8]);
#pragma unroll
    for (int n = 0; n < 4; ++n) bfr[n] = *(const bf16x8*)(&lB[cur][(wn * 64 + n * 16 + c) * 32 + qr * 8]);
    __builtin_amdgcn_s_setprio(1);
#pragma unroll
    for (int m = 0; m < 4; ++m)
#pragma unroll
      for (int n = 0; n < 4; ++n)
        acc[m][n] = __builtin_amdgcn_mfma_f32_16x16x32_bf16(af[m], bfr[n], acc[m][n], 0, 0, 0);
    __builtin_amdgcn_s_setprio(0);
    __syncthreads();
    cur ^= 1;
  }

  const int rb = qr * 4;
#pragma unroll
  for (int m = 0; m < 4; ++m)
#pragma unroll
    for (int n = 0; n < 4; ++n) {
      f32x4 a = acc[m][n];
      int gm0 = brow + wm * 64 + m * 16 + rb;
      int gn = bcol + wn * 64 + n * 16 + c;
#pragma unroll
      for (int r = 0; r < 4; ++r) outp[(size_t)(gm0 + r) * DMODEL + gn] = a[r];
    }
}

// ------------------- causal flash attention (swapped operands, exp2 domain) -------------------
__global__ __launch_bounds__(512, 4) void attn_kernel(const u16* __restrict__ Q, const u16* __restrict__ K,
                                                      const u16* __restrict__ Vt, u16* __restrict__ O) {
  __shared__ u16 lsK[2][64 * 64];
  __shared__ u16 lsV[2][64 * 64];
  __shared__ u16 lsP[8][16 * 64];
  const int hw = blockIdx.x;
  const int xcd = hw & 7, vv = hw >> 3;
  const int by = xcd * 8 + (vv >> 3);  // (b*16+h), grouped per XCD for K/V L2 residency
  const int j = vv & 7;                // pair (j, 15-j) of 128-row q-tiles
  const int tid = threadIdx.x;
  const int w = tid >> 6, lane = tid & 63;
  const int c = lane & 15, qr = lane >> 4;
  const int b = by >> 4, h = by & 15;
  u16* lp = lsP[w];

  const int q0A = j * 128 + w * 16;
  const int q0B = (15 - j) * 128 + w * 16;
  const int ndA = q0A >> 6, ndB = q0B >> 6;
  const int ntiles = 32 - 2 * j;  // always even

  const u16* qra = Q + ((size_t)by * S_LEN + q0A + c) * DHEAD;
  const u16* qrb = Q + ((size_t)by * S_LEN + q0B + c) * DHEAD;
  const bf16x8 aQA0 = *(const bf16x8*)(qra + qr * 8);
  const bf16x8 aQA1 = *(const bf16x8*)(qra + 32 + qr * 8);
  const bf16x8 aQB0 = *(const bf16x8*)(qrb + qr * 8);
  const bf16x8 aQB1 = *(const bf16x8*)(qrb + 32 + qr * 8);

  f32x4 oA[4], oB[4];
#pragma unroll
  for (int d = 0; d < 4; ++d) { oA[d] = (f32x4){0.f, 0.f, 0.f, 0.f}; oB[d] = oA[d]; }
  float mA = -1e30f, lA_ = 0.f, mB = -1e30f, lB_ = 0.f;

  auto stage = [&](int kt, int bsel) {
    const int kv0 = kt * 64;
    int r = tid >> 3, p = tid & 7;
    int ps = p ^ (r & 7);
    gld_lds16(K + ((size_t)by * S_LEN + kv0 + r) * DHEAD + ps * 8, &lsK[bsel][(w * 64) * 8]);
    gld_lds16(Vt + ((size_t)by * DHEAD + r) * S_LEN + kv0 + ps * 8, &lsV[bsel][(w * 64) * 8]);
  };

  auto process = [&](const u16* bK, const u16* bV, int kt, int nd, int q0,
                     const bf16x8& aQ0, const bf16x8& aQ1,
                     f32x4* o_acc, float& m_run, float& l_run) {
    const int kv0 = kt * 64;
    f32x4 sc[4];
    __builtin_amdgcn_s_setprio(1);
#pragma unroll
    for (int nt = 0; nt < 4; ++nt) {
      int row = nt * 16 + c;
      const bf16x8 k0 = *(const bf16x8*)(bK + row * 64 + ((qr ^ (row & 7)) * 8));
      const bf16x8 k1 = *(const bf16x8*)(bK + row * 64 + (((4 + qr) ^ (row & 7)) * 8));
      f32x4 z = (f32x4){0.f, 0.f, 0.f, 0.f};
      z = __builtin_amdgcn_mfma_f32_16x16x32_bf16(k0, aQ0, z, 0, 0, 0);
      z = __builtin_amdgcn_mfma_f32_16x16x32_bf16(k1, aQ1, z, 0, 0, 0);
      sc[nt] = z;
    }
    __builtin_amdgcn_s_setprio(0);

    if (kt == nd) {
#pragma unroll
      for (int nt = 0; nt < 4; ++nt)
#pragma unroll
        for (int r = 0; r < 4; ++r) {
          int k_g = kv0 + nt * 16 + qr * 4 + r;
          int q_g = q0 + c;
          if (k_g > q_g) sc[nt][r] = -1e30f;
        }
    }

    float tm = fmaxf(fmaxf(fmaxf(sc[0][0], sc[0][1]), fmaxf(sc[0][2], sc[0][3])),
                     fmaxf(fmaxf(sc[1][0], sc[1][1]), fmaxf(sc[1][2], sc[1][3])));
    tm = fmaxf(tm, fmaxf(fmaxf(fmaxf(sc[2][0], sc[2][1]), fmaxf(sc[2][2], sc[2][3])),
                         fmaxf(fmaxf(sc[3][0], sc[3][1]), fmaxf(sc[3][2], sc[3][3]))));
    tm = fmaxf(tm, __shfl_xor(tm, 16));
    tm = fmaxf(tm, __shfl_xor(tm, 32));
    if (tm > m_run + 11.5f) {  // defer-max (log2 domain, ~e^8)
      float al = __builtin_amdgcn_exp2f(m_run - tm);
      l_run *= al;
#pragma unroll
      for (int dt = 0; dt < 4; ++dt)
#pragma unroll
        for (int r = 0; r < 4; ++r) o_acc[dt][r] *= al;
      m_run = tm;
    }
    float rs = 0.f;
#pragma unroll
    for (int nt = 0; nt < 4; ++nt) {
      float p0 = __builtin_amdgcn_exp2f(sc[nt][0] - m_run);
      float p1 = __builtin_amdgcn_exp2f(sc[nt][1] - m_run);
      float p2 = __builtin_amdgcn_exp2f(sc[nt][2] - m_run);
      float p3 = __builtin_amdgcn_exp2f(sc[nt][3] - m_run);
      rs += (p0 + p1) + (p2 + p3);
      u32 w01 = __builtin_amdgcn_perm(__builtin_bit_cast(u32, p1), __builtin_bit_cast(u32, p0), 0x07060302u);
      u32 w23 = __builtin_amdgcn_perm(__builtin_bit_cast(u32, p3), __builtin_bit_cast(u32, p2), 0x07060302u);
      uint2 pk; pk.x = w01; pk.y = w23;
      *reinterpret_cast<uint2*>(lp + c * 64 + (((nt * 4 + qr) ^ c) * 4)) = pk;
    }
    rs += __shfl_xor(rs, 16);
    rs += __shfl_xor(rs, 32);
    l_run += rs;

    bf16x8 pb[2];
#pragma unroll
    for (int ks = 0; ks < 2; ++ks) {
      bf16x4 lo = *(const bf16x4*)(lp + c * 64 + (((ks * 8 + qr * 2) ^ c) * 4));
      bf16x4 hi = *(const bf16x4*)(lp + c * 64 + (((ks * 8 + qr * 2 + 1) ^ c) * 4));
      pb[ks] = (bf16x8){lo[0], lo[1], lo[2], lo[3], hi[0], hi[1], hi[2], hi[3]};
    }
    __builtin_amdgcn_s_setprio(1);
#pragma unroll
    for (int dt = 0; dt < 4; ++dt) {
      int rowv = dt * 16 + c;
#pragma unroll
      for (int ks = 0; ks < 2; ++ks) {
        const bf16x8 vb = *(const bf16x8*)(bV + rowv * 64 + (((ks * 4 + qr) ^ (rowv & 7)) * 8));
        o_acc[dt] = __builtin_amdgcn_mfma_f32_16x16x32_bf16(vb, pb[ks], o_acc[dt], 0, 0, 0);
      }
    }
    __builtin_amdgcn_s_setprio(0);
  };

  stage(0, 0);
  __syncthreads();
  for (int kt = 0; kt < ntiles; kt += 2) {
    if (kt + 1 < ntiles) stage(kt + 1, 1);
    if (kt <= ndB) process(lsK[0], lsV[0], kt, ndB, q0B, aQB0, aQB1, oB, mB, lB_);
    if (kt <= ndA) process(lsK[0], lsV[0], kt, ndA, q0A, aQA0, aQA1, oA, mA, lA_);
    __syncthreads();
    const int k2 = kt + 1;
    if (k2 + 1 < ntiles) stage(k2 + 1, 0);
    if (k2 <= ndB) process(lsK[1], lsV[1], k2, ndB, q0B, aQB0, aQB1, oB, mB, lB_);
    if (k2 <= ndA) process(lsK[1], lsV[1], k2, ndA, q0A, aQA0, aQA1, oA, mA, lA_);
    __syncthreads();
  }

  {
    float rl = 1.0f / lB_;
    int s = q0B + c;
#pragma unroll
    for (int dt = 0; dt < 4; ++dt) {
      ushort4 ok;
#pragma unroll
      for (int r = 0; r < 4; ++r) ((u16*)&ok)[r] = f2bf(oB[dt][r] * rl);
      *reinterpret_cast<ushort4*>(O + (((size_t)b * S_LEN + s) * NHEAD + h) * DHEAD + dt * 16 + qr * 4) = ok;
    }
  }
  {
    float rl = 1.0f / lA_;
    int s = q0A + c;
#pragma unroll
    for (int dt = 0; dt < 4; ++dt) {
      ushort4 ok;
#pragma unroll
      for (int r = 0; r < 4; ++r) ((u16*)&ok)[r] = f2bf(oA[dt][r] * rl);
      *reinterpret_cast<ushort4*>(O + (((size_t)b * S_LEN + s) * NHEAD + h) * DHEAD + dt * 16 + qr * 4) = ok;
    }
  }
}

extern "C" void kernel_launch(void* const* d_in, const int* in_sizes, int n_in,
                              void* d_out, int out_size, void* d_ws, size_t ws_size,
                              hipStream_t stream) {
  (void)in_sizes; (void)n_in; (void)out_size; (void)ws_size;
  const float* x  = (const float*)d_in[0];
  const float* Wq = (const float*)d_in[1];
  const float* Wk = (const float*)d_in[2];
  const float* Wv = (const float*)d_in[3];
  const float* Wo = (const float*)d_in[4];

  u16* ws  = (u16*)d_ws;
  u16* xb  = ws;                  // 8192*1024
  u16* wqb = xb  + 8388608;       // [Wq;Wk;Wv;Wo] contiguous
  u16* wob = wqb + 3145728;
  u16* Qb  = wqb + 4194304;       // [B][H][S][DH] (scaled by 0.125*log2e)
  u16* Kb  = Qb  + 8388608;       // [B][H][S][DH]
  u16* Vt  = Kb  + 8388608;       // [B*H][DH][S]
  u16* Ob  = Vt  + 8388608;       // [B][S][H][DH]

  cast_bf16_kernel<<<8192, 256, 0, stream>>>(x, xb, 2097152);
  cast_w_kernel<<<4096, 256, 0, stream>>>(Wq, Wk, Wv, Wo, wqb);

  gemm_qkv<<<512, 512, 0, stream>>>(xb, wqb, Qb);
  attn_kernel<<<512, 512, 0, stream>>>(Qb, Kb, Vt, Ob);
  gemm_bt<<<512, 256, 0, stream>>>(Ob, wob, (float*)d_out);
}